// Round 1
// baseline (834.255 us; speedup 1.0000x reference)
//
#include <hip/hip_runtime.h>
#include <hip/hip_bf16.h>

#define B_  32
#define N_  577
#define D_  768
#define H_  12
#define HD_ 64
#define M_  (B_ * N_)        // 18464 rows
#define VN_ 640              // padded V row stride (multiple of 8, >= 577+63)

typedef __bf16 bf16_t;
typedef __bf16 bf16x8 __attribute__((ext_vector_type(8)));
typedef __bf16 bf16x4 __attribute__((ext_vector_type(4)));
typedef float  f32x4  __attribute__((ext_vector_type(4)));

static __device__ __forceinline__ bf16x8 ldg8(const bf16_t* p) {
    return *reinterpret_cast<const bf16x8*>(p);
}

// ---------------------------------------------------------------- fp32->bf16
__global__ void cvt_f32_bf16(const float* __restrict__ src,
                             bf16_t* __restrict__ dst, int n4) {
    int i = blockIdx.x * blockDim.x + threadIdx.x;
    if (i < n4) {
        float4 f = reinterpret_cast<const float4*>(src)[i];
        bf16x4 o;
        o.x = (bf16_t)f.x; o.y = (bf16_t)f.y; o.z = (bf16_t)f.z; o.w = (bf16_t)f.w;
        *reinterpret_cast<bf16x4*>(dst + (size_t)i * 4) = o;
    }
}

// ---------------------------------------------------------------- bias build
// bias[h][i][j] = table[idx[i][j]*H + h], fp32 (exact vs reference)
__global__ void build_bias(const float* __restrict__ table,
                           const int* __restrict__ idx,
                           float* __restrict__ bias) {
    int i = blockIdx.x;   // q row
    int h = blockIdx.y;   // head
    for (int j = threadIdx.x; j < N_; j += blockDim.x) {
        int id = idx[i * N_ + j];
        bias[((size_t)h * N_ + i) * N_ + j] = table[id * H_ + h];
    }
}

// ---------------------------------------------------------------- QKV GEMM
// out = h @ W^T (+bias).  64x64 tile per block, 4 waves x 16 rows.
// Q,K -> [B,H,N,HD] bf16;  V -> transposed [B,H,HD,VN_] bf16.
__global__ __launch_bounds__(256) void qkv_gemm(
    const bf16_t* __restrict__ hb,
    const bf16_t* __restrict__ wq, const bf16_t* __restrict__ wk,
    const bf16_t* __restrict__ wv,
    const float* __restrict__ qb, const float* __restrict__ vb,
    bf16_t* __restrict__ Q, bf16_t* __restrict__ K, bf16_t* __restrict__ VT)
{
    int tid = threadIdx.x;
    int w = tid >> 6, l = tid & 63, lr = l & 15, lg = l >> 4;
    int rbase = blockIdx.x * 64 + w * 16;
    int cbase = blockIdx.y * 64;

    int arow = rbase + lr;
    int arow_c = arow < M_ ? arow : (M_ - 1);
    const bf16_t* ap = hb + (size_t)arow_c * D_ + lg * 8;

    const bf16_t* wp0 = wq + ((size_t)(cbase + lr)) * D_ + lg * 8;
    const bf16_t* wp1 = wk + ((size_t)(cbase + lr)) * D_ + lg * 8;
    const bf16_t* wp2 = wv + ((size_t)(cbase + lr)) * D_ + lg * 8;

    f32x4 acc[3][4] = {};

    for (int kc = 0; kc < D_; kc += 32) {
        bf16x8 a = ldg8(ap + kc);
#pragma unroll
        for (int ct = 0; ct < 4; ++ct) {
            bf16x8 b0 = ldg8(wp0 + (size_t)ct * 16 * D_ + kc);
            acc[0][ct] = __builtin_amdgcn_mfma_f32_16x16x32_bf16(a, b0, acc[0][ct], 0, 0, 0);
            bf16x8 b1 = ldg8(wp1 + (size_t)ct * 16 * D_ + kc);
            acc[1][ct] = __builtin_amdgcn_mfma_f32_16x16x32_bf16(a, b1, acc[1][ct], 0, 0, 0);
            bf16x8 b2 = ldg8(wp2 + (size_t)ct * 16 * D_ + kc);
            acc[2][ct] = __builtin_amdgcn_mfma_f32_16x16x32_bf16(a, b2, acc[2][ct], 0, 0, 0);
        }
    }

    // epilogue: D layout col=lane&15, row=(lane>>4)*4+reg
#pragma unroll
    for (int j = 0; j < 4; ++j) {
        int row = rbase + lg * 4 + j;
        if (row >= M_) continue;
        int bb = row / N_;
        int nn = row - bb * N_;
#pragma unroll
        for (int ct = 0; ct < 4; ++ct) {
            int col = cbase + ct * 16 + lr;
            int hh = col >> 6, hd = col & 63;
            size_t qidx = ((size_t)(bb * H_ + hh) * N_ + nn) * HD_ + hd;
            Q[qidx] = (bf16_t)(acc[0][ct][j] + qb[col]);
            K[qidx] = (bf16_t)(acc[1][ct][j]);
            VT[((size_t)(bb * H_ + hh) * HD_ + hd) * VN_ + nn] =
                (bf16_t)(acc[2][ct][j] + vb[col]);
        }
    }
}

// ---------------------------------------------------------------- attention
// block = (qtile of 64, head, batch); 4 waves x 16 q-rows; flash-style.
__global__ __launch_bounds__(256) void attn(
    const bf16_t* __restrict__ Q, const bf16_t* __restrict__ K,
    const bf16_t* __restrict__ VT, const float* __restrict__ bias,
    float* __restrict__ out)
{
    __shared__ char Pl[4 * 2048];   // per-wave 16x64 bf16 P tile, XOR-swizzled

    int tid = threadIdx.x;
    int w = tid >> 6, l = tid & 63, lr = l & 15, lg = l >> 4;
    int qt = blockIdx.x, h = blockIdx.y, b = blockIdx.z;

    const bf16_t* Qp = Q  + (size_t)(b * H_ + h) * N_ * HD_;
    const bf16_t* Kp = K  + (size_t)(b * H_ + h) * N_ * HD_;
    const bf16_t* Vp = VT + (size_t)(b * H_ + h) * HD_ * VN_;
    const float*  bp = bias + (size_t)h * N_ * N_;

    int q0 = qt * 64 + w * 16;
    int qrow = q0 + lr;
    int qrow_c = qrow < N_ ? qrow : (N_ - 1);
    bf16x8 aQ0 = ldg8(Qp + (size_t)qrow_c * HD_ + lg * 8);
    bf16x8 aQ1 = ldg8(Qp + (size_t)qrow_c * HD_ + 32 + lg * 8);

    f32x4 o[4] = {};
    float mr[4] = {-INFINITY, -INFINITY, -INFINITY, -INFINITY};
    float sr[4] = {0.f, 0.f, 0.f, 0.f};
    int rown[4];
#pragma unroll
    for (int j = 0; j < 4; ++j) {
        int r = q0 + lg * 4 + j;
        rown[j] = r < N_ ? r : (N_ - 1);
    }
    char* Pw = Pl + w * 2048;

    for (int k0 = 0; k0 < N_; k0 += 64) {
        // S = Q K^T  (per-wave 16x64, 4 col fragments)
        f32x4 s[4];
#pragma unroll
        for (int kt = 0; kt < 4; ++kt) {
            int key = k0 + kt * 16 + lr;
            int key_c = key < N_ ? key : (N_ - 1);
            f32x4 a = {};
            a = __builtin_amdgcn_mfma_f32_16x16x32_bf16(
                    aQ0, ldg8(Kp + (size_t)key_c * HD_ + lg * 8), a, 0, 0, 0);
            a = __builtin_amdgcn_mfma_f32_16x16x32_bf16(
                    aQ1, ldg8(Kp + (size_t)key_c * HD_ + 32 + lg * 8), a, 0, 0, 0);
            s[kt] = a;
        }
        // scale + bias + key mask
#pragma unroll
        for (int kt = 0; kt < 4; ++kt) {
            int col = k0 + kt * 16 + lr;
            bool colv = col < N_;
            int col_c = colv ? col : (N_ - 1);
#pragma unroll
            for (int j = 0; j < 4; ++j) {
                float v = s[kt][j] * 0.125f + bp[(size_t)rown[j] * N_ + col_c];
                s[kt][j] = colv ? v : -1e30f;
            }
        }
        // online softmax (rows live in lanes with same lg; reduce over lanes 0-15)
#pragma unroll
        for (int j = 0; j < 4; ++j) {
            float mx = fmaxf(fmaxf(s[0][j], s[1][j]), fmaxf(s[2][j], s[3][j]));
#pragma unroll
            for (int d = 1; d < 16; d <<= 1) mx = fmaxf(mx, __shfl_xor(mx, d));
            float mn = fmaxf(mr[j], mx);
            float sc = __expf(mr[j] - mn);   // exp(-inf)=0 on first tile
            mr[j] = mn;
            float rs = 0.f;
#pragma unroll
            for (int kt = 0; kt < 4; ++kt) {
                float p = __expf(s[kt][j] - mn);
                s[kt][j] = p;
                rs += p;
            }
#pragma unroll
            for (int d = 1; d < 16; d <<= 1) rs += __shfl_xor(rs, d);
            sr[j] = sr[j] * sc + rs;
            o[0][j] *= sc; o[1][j] *= sc; o[2][j] *= sc; o[3][j] *= sc;
        }
        // P -> LDS (bf16, XOR swizzle byte ^= (row&7)<<4)
#pragma unroll
        for (int kt = 0; kt < 4; ++kt) {
#pragma unroll
            for (int j = 0; j < 4; ++j) {
                int row = lg * 4 + j;
                int byte = row * 128 + (kt * 16 + lr) * 2;
                byte ^= (row & 7) << 4;
                *reinterpret_cast<bf16_t*>(Pw + byte) = (bf16_t)s[kt][j];
            }
        }
        // O += P V   (A = P from LDS, B = V^T rows -> contiguous keys)
#pragma unroll
        for (int kc = 0; kc < 2; ++kc) {
            int byte = lr * 128 + kc * 64 + lg * 16;
            byte ^= (lr & 7) << 4;
            bf16x8 aP = *reinterpret_cast<const bf16x8*>(Pw + byte);
#pragma unroll
            for (int ft = 0; ft < 4; ++ft) {
                bf16x8 bV = ldg8(Vp + (size_t)(ft * 16 + lr) * VN_ + k0 + kc * 32 + lg * 8);
                o[ft] = __builtin_amdgcn_mfma_f32_16x16x32_bf16(aP, bV, o[ft], 0, 0, 0);
            }
        }
    }
    // store: out[b, row, h*64 + ft*16 + lr]
#pragma unroll
    for (int j = 0; j < 4; ++j) {
        int row = q0 + lg * 4 + j;
        if (row < N_) {
            float inv = 1.f / sr[j];
#pragma unroll
            for (int ft = 0; ft < 4; ++ft) {
                out[((size_t)(b * N_ + row)) * D_ + h * HD_ + ft * 16 + lr] = o[ft][j] * inv;
            }
        }
    }
}

// ---------------------------------------------------------------- launch
extern "C" void kernel_launch(void* const* d_in, const int* in_sizes, int n_in,
                              void* d_out, int out_size, void* d_ws, size_t ws_size,
                              hipStream_t stream)
{
    const float* hs    = (const float*)d_in[0];
    const float* q_w   = (const float*)d_in[1];
    const float* q_b   = (const float*)d_in[2];
    const float* k_w   = (const float*)d_in[3];
    const float* v_w   = (const float*)d_in[4];
    const float* v_b   = (const float*)d_in[5];
    const float* table = (const float*)d_in[6];
    const int*   rpi   = (const int*)d_in[7];
    float* out = (float*)d_out;

    char* ws = (char*)d_ws;
    size_t off = 0;
    auto alloc = [&](size_t bytes) {
        char* p = ws + off;
        off = (off + bytes + 255) & ~(size_t)255;
        return p;
    };
    bf16_t* hb  = (bf16_t*)alloc((size_t)M_ * D_ * 2);
    bf16_t* wqb = (bf16_t*)alloc((size_t)D_ * D_ * 2);
    bf16_t* wkb = (bf16_t*)alloc((size_t)D_ * D_ * 2);
    bf16_t* wvb = (bf16_t*)alloc((size_t)D_ * D_ * 2);
    bf16_t* Qb  = (bf16_t*)alloc((size_t)B_ * H_ * N_ * HD_ * 2);
    bf16_t* Kb  = (bf16_t*)alloc((size_t)B_ * H_ * N_ * HD_ * 2);
    size_t vt_bytes = (size_t)B_ * H_ * HD_ * VN_ * 2;
    bf16_t* VTb = (bf16_t*)alloc(vt_bytes);
    float*  bia = (float*)alloc((size_t)H_ * N_ * N_ * 4);

    int n4h = M_ * D_ / 4;
    cvt_f32_bf16<<<(n4h + 255) / 256, 256, 0, stream>>>(hs, hb, n4h);
    int n4w = D_ * D_ / 4;
    cvt_f32_bf16<<<(n4w + 255) / 256, 256, 0, stream>>>(q_w, wqb, n4w);
    cvt_f32_bf16<<<(n4w + 255) / 256, 256, 0, stream>>>(k_w, wkb, n4w);
    cvt_f32_bf16<<<(n4w + 255) / 256, 256, 0, stream>>>(v_w, wvb, n4w);
    hipMemsetAsync(VTb, 0, vt_bytes, stream);  // zero V padding (avoid NaN garbage)
    build_bias<<<dim3(N_, H_), 256, 0, stream>>>(table, rpi, bia);

    qkv_gemm<<<dim3((M_ + 63) / 64, D_ / 64), 256, 0, stream>>>(
        hb, wqb, wkb, wvb, q_b, v_b, Qb, Kb, VTb);

    attn<<<dim3((N_ + 63) / 64, H_, B_), 256, 0, stream>>>(Qb, Kb, VTb, bia, out);
}

// Round 2
// 506.267 us; speedup vs baseline: 1.6479x; 1.6479x over previous
//
#include <hip/hip_runtime.h>
#include <hip/hip_bf16.h>

#define B_  32
#define N_  577
#define D_  768
#define H_  12
#define HD_ 64
#define M_  (B_ * N_)        // 18464 rows
#define NW_ (3 * D_)         // 2304 fused output cols (q|k|v)
#define VN_ 640              // padded V row stride

typedef __bf16 bf16_t;
typedef __bf16 bf16x8 __attribute__((ext_vector_type(8)));
typedef __bf16 bf16x4 __attribute__((ext_vector_type(4)));
typedef float  f32x4  __attribute__((ext_vector_type(4)));

static __device__ __forceinline__ bf16x8 ldg8(const bf16_t* p) {
    return *reinterpret_cast<const bf16x8*>(p);
}

#define GLOAD_LDS16(g, l)                                                     \
    __builtin_amdgcn_global_load_lds(                                         \
        (const __attribute__((address_space(1))) void*)(g),                   \
        (__attribute__((address_space(3))) void*)(l), 16, 0, 0)

// ---------------------------------------------------------------- fp32->bf16
__global__ void cvt_f32_bf16(const float* __restrict__ src,
                             bf16_t* __restrict__ dst, int n4) {
    int i = blockIdx.x * blockDim.x + threadIdx.x;
    if (i < n4) {
        float4 f = reinterpret_cast<const float4*>(src)[i];
        bf16x4 o;
        o.x = (bf16_t)f.x; o.y = (bf16_t)f.y; o.z = (bf16_t)f.z; o.w = (bf16_t)f.w;
        *reinterpret_cast<bf16x4*>(dst + (size_t)i * 4) = o;
    }
}

// ---------------------------------------------------------------- bias build
__global__ void build_bias(const float* __restrict__ table,
                           const int* __restrict__ idx,
                           float* __restrict__ bias) {
    int i = blockIdx.x;   // q row
    int h = blockIdx.y;   // head
    for (int j = threadIdx.x; j < N_; j += blockDim.x) {
        int id = idx[i * N_ + j];
        bias[((size_t)h * N_ + i) * N_ + j] = table[id * H_ + h];
    }
}

// ---------------------------------------------------------------- QKV GEMM
// C[M_ x NW_] = hb @ Wcat^T, m97 structure: 128x128 tile, BK=32,
// global_load_lds(16B) staging, 4 waves x (4x4 16x16 frags).
// Epilogue scatters to Q,K [B,H,N,64] and VT [B,H,64,VN_] with biases.
__global__ __launch_bounds__(256) void qkv_gemm(
    const bf16_t* __restrict__ hb, const bf16_t* __restrict__ W,
    const float* __restrict__ qb, const float* __restrict__ vb,
    bf16_t* __restrict__ Q, bf16_t* __restrict__ K, bf16_t* __restrict__ VT)
{
    __shared__ __align__(16) char ldsA[8192];   // [128][32] bf16, row stride 64B
    __shared__ __align__(16) char ldsB[8192];   // [128 cols][32] bf16

    int tid = threadIdx.x;
    int w  = tid >> 6, l = tid & 63;
    int lr = l & 15, lg = l >> 4;
    int wm = w & 1,  wn = w >> 1;

    int brow = blockIdx.x * 128;
    int bcol = blockIdx.y * 128;

    // staging coords: chunk = 16 rows (1024B); wave w owns chunks {w, w+4}
    int srow0 = (l >> 2);          // 0..15 within chunk
    int scol  = (l & 3) * 8;       // 0,8,16,24

    f32x4 acc[4][4] = {};

    for (int k0 = 0; k0 < D_; k0 += 32) {
#pragma unroll
        for (int i = 0; i < 2; ++i) {
            int chunk = w + i * 4;             // 0..7
            int row = chunk * 16 + srow0;
            int ga = brow + row; ga = ga < M_ ? ga : (M_ - 1);
            GLOAD_LDS16(hb + (size_t)ga * D_ + k0 + scol, ldsA + chunk * 1024);
            GLOAD_LDS16(W + (size_t)(bcol + row) * D_ + k0 + scol,
                        ldsB + chunk * 1024);
        }
        __syncthreads();

        bf16x8 af[4];
#pragma unroll
        for (int m = 0; m < 4; ++m)
            af[m] = *reinterpret_cast<const bf16x8*>(
                ldsA + (wm * 64 + m * 16 + lr) * 64 + lg * 16);
#pragma unroll
        for (int n = 0; n < 4; ++n) {
            bf16x8 bfr = *reinterpret_cast<const bf16x8*>(
                ldsB + (wn * 64 + n * 16 + lr) * 64 + lg * 16);
#pragma unroll
            for (int m = 0; m < 4; ++m)
                acc[m][n] = __builtin_amdgcn_mfma_f32_16x16x32_bf16(
                    af[m], bfr, acc[m][n], 0, 0, 0);
        }
        __syncthreads();
    }

    // epilogue: D layout col=lane&15, row=(lane>>4)*4+reg
    int mat = bcol / D_;                       // 0=q 1=k 2=v (block-uniform)
    int cb0 = bcol - mat * D_ + wn * 64;       // col within matrix
#pragma unroll
    for (int m = 0; m < 4; ++m) {
#pragma unroll
        for (int j = 0; j < 4; ++j) {
            int row = brow + wm * 64 + m * 16 + lg * 4 + j;
            if (row >= M_) continue;
            int bb = row / N_;
            int nn = row - bb * N_;
#pragma unroll
            for (int n = 0; n < 4; ++n) {
                int c  = cb0 + n * 16 + lr;
                int hh = c >> 6, hd = c & 63;
                float v = acc[m][n][j];
                if (mat == 0) {
                    Q[((size_t)(bb * H_ + hh) * N_ + nn) * HD_ + hd] =
                        (bf16_t)(v + qb[c]);
                } else if (mat == 1) {
                    K[((size_t)(bb * H_ + hh) * N_ + nn) * HD_ + hd] = (bf16_t)v;
                } else {
                    VT[((size_t)(bb * H_ + hh) * HD_ + hd) * VN_ + nn] =
                        (bf16_t)(v + vb[c]);
                }
            }
        }
    }
}

// ---------------------------------------------------------------- attention
__global__ __launch_bounds__(256) void attn(
    const bf16_t* __restrict__ Q, const bf16_t* __restrict__ K,
    const bf16_t* __restrict__ VT, const float* __restrict__ bias,
    float* __restrict__ out)
{
    __shared__ char Pl[4 * 2048];   // per-wave 16x64 bf16 P tile, XOR-swizzled

    int tid = threadIdx.x;
    int w = tid >> 6, l = tid & 63, lr = l & 15, lg = l >> 4;
    int qt = blockIdx.x, h = blockIdx.y, b = blockIdx.z;

    const bf16_t* Qp = Q  + (size_t)(b * H_ + h) * N_ * HD_;
    const bf16_t* Kp = K  + (size_t)(b * H_ + h) * N_ * HD_;
    const bf16_t* Vp = VT + (size_t)(b * H_ + h) * HD_ * VN_;
    const float*  bp = bias + (size_t)h * N_ * N_;

    int q0 = qt * 64 + w * 16;
    int qrow = q0 + lr;
    int qrow_c = qrow < N_ ? qrow : (N_ - 1);
    bf16x8 aQ0 = ldg8(Qp + (size_t)qrow_c * HD_ + lg * 8);
    bf16x8 aQ1 = ldg8(Qp + (size_t)qrow_c * HD_ + 32 + lg * 8);

    f32x4 o[4] = {};
    float mr[4] = {-INFINITY, -INFINITY, -INFINITY, -INFINITY};
    float sr[4] = {0.f, 0.f, 0.f, 0.f};
    int rown[4];
#pragma unroll
    for (int j = 0; j < 4; ++j) {
        int r = q0 + lg * 4 + j;
        rown[j] = r < N_ ? r : (N_ - 1);
    }
    char* Pw = Pl + w * 2048;

    for (int k0 = 0; k0 < N_; k0 += 64) {
        f32x4 s[4];
#pragma unroll
        for (int kt = 0; kt < 4; ++kt) {
            int key = k0 + kt * 16 + lr;
            int key_c = key < N_ ? key : (N_ - 1);
            f32x4 a = {};
            a = __builtin_amdgcn_mfma_f32_16x16x32_bf16(
                    aQ0, ldg8(Kp + (size_t)key_c * HD_ + lg * 8), a, 0, 0, 0);
            a = __builtin_amdgcn_mfma_f32_16x16x32_bf16(
                    aQ1, ldg8(Kp + (size_t)key_c * HD_ + 32 + lg * 8), a, 0, 0, 0);
            s[kt] = a;
        }
#pragma unroll
        for (int kt = 0; kt < 4; ++kt) {
            int col = k0 + kt * 16 + lr;
            bool colv = col < N_;
            int col_c = colv ? col : (N_ - 1);
#pragma unroll
            for (int j = 0; j < 4; ++j) {
                float v = s[kt][j] * 0.125f + bp[(size_t)rown[j] * N_ + col_c];
                s[kt][j] = colv ? v : -1e30f;
            }
        }
#pragma unroll
        for (int j = 0; j < 4; ++j) {
            float mx = fmaxf(fmaxf(s[0][j], s[1][j]), fmaxf(s[2][j], s[3][j]));
#pragma unroll
            for (int d = 1; d < 16; d <<= 1) mx = fmaxf(mx, __shfl_xor(mx, d));
            float mn = fmaxf(mr[j], mx);
            float sc = __expf(mr[j] - mn);
            mr[j] = mn;
            float rs = 0.f;
#pragma unroll
            for (int kt = 0; kt < 4; ++kt) {
                float p = __expf(s[kt][j] - mn);
                s[kt][j] = p;
                rs += p;
            }
#pragma unroll
            for (int d = 1; d < 16; d <<= 1) rs += __shfl_xor(rs, d);
            sr[j] = sr[j] * sc + rs;
            o[0][j] *= sc; o[1][j] *= sc; o[2][j] *= sc; o[3][j] *= sc;
        }
#pragma unroll
        for (int kt = 0; kt < 4; ++kt) {
#pragma unroll
            for (int j = 0; j < 4; ++j) {
                int row = lg * 4 + j;
                int byte = row * 128 + (kt * 16 + lr) * 2;
                byte ^= (row & 7) << 4;
                *reinterpret_cast<bf16_t*>(Pw + byte) = (bf16_t)s[kt][j];
            }
        }
#pragma unroll
        for (int kc = 0; kc < 2; ++kc) {
            int byte = lr * 128 + kc * 64 + lg * 16;
            byte ^= (lr & 7) << 4;
            bf16x8 aP = *reinterpret_cast<const bf16x8*>(Pw + byte);
#pragma unroll
            for (int ft = 0; ft < 4; ++ft) {
                bf16x8 bV = ldg8(Vp + (size_t)(ft * 16 + lr) * VN_ + k0 + kc * 32 + lg * 8);
                o[ft] = __builtin_amdgcn_mfma_f32_16x16x32_bf16(aP, bV, o[ft], 0, 0, 0);
            }
        }
    }
#pragma unroll
    for (int j = 0; j < 4; ++j) {
        int row = q0 + lg * 4 + j;
        if (row < N_) {
            float inv = 1.f / sr[j];
#pragma unroll
            for (int ft = 0; ft < 4; ++ft) {
                out[((size_t)(b * N_ + row)) * D_ + h * HD_ + ft * 16 + lr] = o[ft][j] * inv;
            }
        }
    }
}

// ---------------------------------------------------------------- launch
extern "C" void kernel_launch(void* const* d_in, const int* in_sizes, int n_in,
                              void* d_out, int out_size, void* d_ws, size_t ws_size,
                              hipStream_t stream)
{
    const float* hs    = (const float*)d_in[0];
    const float* q_w   = (const float*)d_in[1];
    const float* q_b   = (const float*)d_in[2];
    const float* k_w   = (const float*)d_in[3];
    const float* v_w   = (const float*)d_in[4];
    const float* v_b   = (const float*)d_in[5];
    const float* table = (const float*)d_in[6];
    const int*   rpi   = (const int*)d_in[7];
    float* out = (float*)d_out;

    char* ws = (char*)d_ws;
    size_t off = 0;
    auto alloc = [&](size_t bytes) {
        char* p = ws + off;
        off = (off + bytes + 255) & ~(size_t)255;
        return p;
    };
    bf16_t* hb  = (bf16_t*)alloc((size_t)M_ * D_ * 2);
    bf16_t* Wc  = (bf16_t*)alloc((size_t)NW_ * D_ * 2);   // q|k|v rows
    bf16_t* Qb  = (bf16_t*)alloc((size_t)B_ * H_ * N_ * HD_ * 2);
    bf16_t* Kb  = (bf16_t*)alloc((size_t)B_ * H_ * N_ * HD_ * 2);
    size_t vt_bytes = (size_t)B_ * H_ * HD_ * VN_ * 2;
    bf16_t* VTb = (bf16_t*)alloc(vt_bytes);
    float*  bia = (float*)alloc((size_t)H_ * N_ * N_ * 4);

    int n4h = M_ * D_ / 4;
    cvt_f32_bf16<<<(n4h + 255) / 256, 256, 0, stream>>>(hs, hb, n4h);
    int n4w = D_ * D_ / 4;
    cvt_f32_bf16<<<(n4w + 255) / 256, 256, 0, stream>>>(q_w, Wc, n4w);
    cvt_f32_bf16<<<(n4w + 255) / 256, 256, 0, stream>>>(k_w, Wc + (size_t)D_ * D_, n4w);
    cvt_f32_bf16<<<(n4w + 255) / 256, 256, 0, stream>>>(v_w, Wc + (size_t)2 * D_ * D_, n4w);
    hipMemsetAsync(VTb, 0, vt_bytes, stream);
    build_bias<<<dim3(N_, H_), 256, 0, stream>>>(table, rpi, bia);

    qkv_gemm<<<dim3((M_ + 127) / 128, NW_ / 128), 256, 0, stream>>>(
        hb, Wc, q_b, v_b, Qb, Kb, VTb);

    attn<<<dim3((N_ + 63) / 64, H_, B_), 256, 0, stream>>>(Qb, Kb, VTb, bia, out);
}

// Round 3
// 377.587 us; speedup vs baseline: 2.2094x; 1.3408x over previous
//
#include <hip/hip_runtime.h>
#include <hip/hip_bf16.h>

#define B_  32
#define N_  577
#define D_  768
#define H_  12
#define HD_ 64
#define M_  (B_ * N_)        // 18464 rows
#define NW_ (3 * D_)         // 2304 fused output cols (q|k|v)
#define VN_ 640              // padded V row stride
#define BPAD_ 580            // bias row-dim padding (mult of 4)
#define SCALE_ 0.18033688f   // 0.125 * log2(e)

typedef __bf16 bf16_t;
typedef __bf16 bf16x8 __attribute__((ext_vector_type(8)));
typedef __bf16 bf16x4 __attribute__((ext_vector_type(4)));
typedef float  f32x4  __attribute__((ext_vector_type(4)));

static __device__ __forceinline__ bf16x8 ldg8(const bf16_t* p) {
    return *reinterpret_cast<const bf16x8*>(p);
}

#define GLOAD_LDS16(g, l)                                                     \
    __builtin_amdgcn_global_load_lds(                                         \
        (const __attribute__((address_space(1))) void*)(g),                   \
        (__attribute__((address_space(3))) void*)(l), 16, 0, 0)

// ---------------------------------------------------------------- fp32->bf16
__global__ void cvt_f32_bf16(const float* __restrict__ src,
                             bf16_t* __restrict__ dst, int n4) {
    int i = blockIdx.x * blockDim.x + threadIdx.x;
    if (i < n4) {
        float4 f = reinterpret_cast<const float4*>(src)[i];
        bf16x4 o;
        o.x = (bf16_t)f.x; o.y = (bf16_t)f.y; o.z = (bf16_t)f.z; o.w = (bf16_t)f.w;
        *reinterpret_cast<bf16x4*>(dst + (size_t)i * 4) = o;
    }
}

// ---------------------------------------------------------------- bias build
// biasT[h][col][row] = table[idx[row][col]*H + h] * log2(e)   (row padded)
__global__ void build_bias_t(const float* __restrict__ table,
                             const int* __restrict__ idx,
                             float* __restrict__ biasT) {
    int col = blockIdx.x;   // key col
    int h   = blockIdx.y;   // head
    for (int row = threadIdx.x; row < BPAD_; row += blockDim.x) {
        int rr = row < N_ ? row : (N_ - 1);
        int id = idx[rr * N_ + col];
        biasT[((size_t)h * N_ + col) * BPAD_ + row] =
            table[id * H_ + h] * 1.44269504f;
    }
}

// ---------------------------------------------------------------- QKV GEMM
__global__ __launch_bounds__(256) void qkv_gemm(
    const bf16_t* __restrict__ hb, const bf16_t* __restrict__ W,
    const float* __restrict__ qb, const float* __restrict__ vb,
    bf16_t* __restrict__ Q, bf16_t* __restrict__ K, bf16_t* __restrict__ VT)
{
    __shared__ __align__(16) char ldsA[8192];   // [128][32] bf16
    __shared__ __align__(16) char ldsB[8192];

    int tid = threadIdx.x;
    int w  = tid >> 6, l = tid & 63;
    int lr = l & 15, lg = l >> 4;
    int wm = w & 1,  wn = w >> 1;

    int brow = blockIdx.x * 128;
    int bcol = blockIdx.y * 128;

    int srow0 = (l >> 2);
    int scol  = (l & 3) * 8;

    f32x4 acc[4][4] = {};

    for (int k0 = 0; k0 < D_; k0 += 32) {
#pragma unroll
        for (int i = 0; i < 2; ++i) {
            int chunk = w + i * 4;
            int row = chunk * 16 + srow0;
            int ga = brow + row; ga = ga < M_ ? ga : (M_ - 1);
            GLOAD_LDS16(hb + (size_t)ga * D_ + k0 + scol, ldsA + chunk * 1024);
            GLOAD_LDS16(W + (size_t)(bcol + row) * D_ + k0 + scol,
                        ldsB + chunk * 1024);
        }
        __syncthreads();

        bf16x8 af[4];
#pragma unroll
        for (int m = 0; m < 4; ++m)
            af[m] = *reinterpret_cast<const bf16x8*>(
                ldsA + (wm * 64 + m * 16 + lr) * 64 + lg * 16);
#pragma unroll
        for (int n = 0; n < 4; ++n) {
            bf16x8 bfr = *reinterpret_cast<const bf16x8*>(
                ldsB + (wn * 64 + n * 16 + lr) * 64 + lg * 16);
#pragma unroll
            for (int m = 0; m < 4; ++m)
                acc[m][n] = __builtin_amdgcn_mfma_f32_16x16x32_bf16(
                    af[m], bfr, acc[m][n], 0, 0, 0);
        }
        __syncthreads();
    }

    int mat = bcol / D_;
    int cb0 = bcol - mat * D_ + wn * 64;
#pragma unroll
    for (int m = 0; m < 4; ++m) {
#pragma unroll
        for (int j = 0; j < 4; ++j) {
            int row = brow + wm * 64 + m * 16 + lg * 4 + j;
            if (row >= M_) continue;
            int bb = row / N_;
            int nn = row - bb * N_;
#pragma unroll
            for (int n = 0; n < 4; ++n) {
                int c  = cb0 + n * 16 + lr;
                int hh = c >> 6, hd = c & 63;
                float v = acc[m][n][j];
                if (mat == 0) {
                    Q[((size_t)(bb * H_ + hh) * N_ + nn) * HD_ + hd] =
                        (bf16_t)(v + qb[c]);
                } else if (mat == 1) {
                    K[((size_t)(bb * H_ + hh) * N_ + nn) * HD_ + hd] = (bf16_t)v;
                } else {
                    VT[((size_t)(bb * H_ + hh) * HD_ + hd) * VN_ + nn] =
                        (bf16_t)(v + vb[c]);
                }
            }
        }
    }
}

// ---------------------------------------------------------------- attention
// 4 waves x 16 q-rows; K,V tiles LDS-staged (XOR-swizzled), double-buffered.
__global__ __launch_bounds__(256) void attn(
    const bf16_t* __restrict__ Q, const bf16_t* __restrict__ K,
    const bf16_t* __restrict__ VT, const float* __restrict__ biasT,
    float* __restrict__ out)
{
    __shared__ __align__(16) char Kl[2][8192];   // [64 key][64 hd] bf16, swz
    __shared__ __align__(16) char Vl[2][8192];   // [64 d][64 key] bf16, swz
    __shared__ __align__(16) char Pl[4][2048];   // per-wave P, swz

    int tid = threadIdx.x;
    int w = tid >> 6, l = tid & 63, lr = l & 15, lg = l >> 4;
    int qt = blockIdx.x, h = blockIdx.y, b = blockIdx.z;

    const bf16_t* Qp = Q  + (size_t)(b * H_ + h) * N_ * HD_;
    const bf16_t* Kp = K  + (size_t)(b * H_ + h) * N_ * HD_;
    const bf16_t* Vp = VT + (size_t)(b * H_ + h) * HD_ * VN_;
    const float*  bp = biasT + (size_t)h * N_ * BPAD_;   // [col][row]

    int q0 = qt * 64 + w * 16;
    int qrow = q0 + lr;
    int qrow_c = qrow < N_ ? qrow : (N_ - 1);
    bf16x8 aQ0 = ldg8(Qp + (size_t)qrow_c * HD_ + lg * 8);
    bf16x8 aQ1 = ldg8(Qp + (size_t)qrow_c * HD_ + 32 + lg * 8);

    // staging geometry: lane lands at (wave base + l*16); within a 1024B chunk
    // row = l>>3, col16 = l&7; source pre-swizzled: col16 ^= row
    int rloc = l >> 3;              // 0..7
    int cswz = (l & 7) ^ rloc;      // swizzled 8-elem column

    f32x4 o[4] = {};
    float mr[4] = {-INFINITY, -INFINITY, -INFINITY, -INFINITY};
    float sr[4] = {0.f, 0.f, 0.f, 0.f};
    char* Pw = Pl[w];

    auto stage = [&](int buf, int k0) {
#pragma unroll
        for (int round = 0; round < 2; ++round) {
            int r = round * 32 + w * 8 + rloc;           // tile row 0..63
            int kr = k0 + r; kr = kr < N_ ? kr : (N_ - 1);
            GLOAD_LDS16(Kp + (size_t)kr * HD_ + cswz * 8,
                        Kl[buf] + round * 4096 + w * 1024);
            GLOAD_LDS16(Vp + (size_t)r * VN_ + k0 + cswz * 8,
                        Vl[buf] + round * 4096 + w * 1024);
        }
    };

    stage(0, 0);
    __syncthreads();

    int cur = 0;
    const int NT = (N_ + 63) / 64;   // 10
    for (int t = 0; t < NT; ++t) {
        int k0 = t * 64;
        if (t + 1 < NT) stage(cur ^ 1, k0 + 64);

        // S = Q K^T from LDS (swizzled reads)
        f32x4 s[4];
#pragma unroll
        for (int kt = 0; kt < 4; ++kt) {
            int r = kt * 16 + lr;
            bf16x8 kf0 = *reinterpret_cast<const bf16x8*>(
                Kl[cur] + r * 128 + ((lg ^ (r & 7)) << 4));
            bf16x8 kf1 = *reinterpret_cast<const bf16x8*>(
                Kl[cur] + r * 128 + (((4 + lg) ^ (r & 7)) << 4));
            f32x4 a = {};
            a = __builtin_amdgcn_mfma_f32_16x16x32_bf16(aQ0, kf0, a, 0, 0, 0);
            a = __builtin_amdgcn_mfma_f32_16x16x32_bf16(aQ1, kf1, a, 0, 0, 0);
            s[kt] = a;
        }
        // scale + bias (transposed, float4 per kt) + key mask; log2 domain
#pragma unroll
        for (int kt = 0; kt < 4; ++kt) {
            int col = k0 + kt * 16 + lr;
            bool colv = col < N_;
            int col_c = colv ? col : (N_ - 1);
            f32x4 bb = *reinterpret_cast<const f32x4*>(
                bp + (size_t)col_c * BPAD_ + q0 + lg * 4);
#pragma unroll
            for (int j = 0; j < 4; ++j) {
                float v = s[kt][j] * SCALE_ + bb[j];
                s[kt][j] = colv ? v : -1e30f;
            }
        }
        // online softmax (exp2 domain)
#pragma unroll
        for (int j = 0; j < 4; ++j) {
            float mx = fmaxf(fmaxf(s[0][j], s[1][j]), fmaxf(s[2][j], s[3][j]));
#pragma unroll
            for (int d = 1; d < 16; d <<= 1) mx = fmaxf(mx, __shfl_xor(mx, d));
            float mn = fmaxf(mr[j], mx);
            float sc = __builtin_amdgcn_exp2f(mr[j] - mn);
            mr[j] = mn;
            float rs = 0.f;
#pragma unroll
            for (int kt = 0; kt < 4; ++kt) {
                float p = __builtin_amdgcn_exp2f(s[kt][j] - mn);
                s[kt][j] = p;
                rs += p;
            }
#pragma unroll
            for (int d = 1; d < 16; d <<= 1) rs += __shfl_xor(rs, d);
            sr[j] = sr[j] * sc + rs;
            o[0][j] *= sc; o[1][j] *= sc; o[2][j] *= sc; o[3][j] *= sc;
        }
        // P -> per-wave LDS (swizzled)
#pragma unroll
        for (int kt = 0; kt < 4; ++kt) {
#pragma unroll
            for (int j = 0; j < 4; ++j) {
                int row = lg * 4 + j;
                int byte = row * 128 + (kt * 16 + lr) * 2;
                byte ^= (row & 7) << 4;
                *reinterpret_cast<bf16_t*>(Pw + byte) = (bf16_t)s[kt][j];
            }
        }
        // O += P V from LDS
#pragma unroll
        for (int kc = 0; kc < 2; ++kc) {
            int pbyte = lr * 128 + kc * 64 + lg * 16;
            pbyte ^= (lr & 7) << 4;
            bf16x8 aP = *reinterpret_cast<const bf16x8*>(Pw + pbyte);
#pragma unroll
            for (int ft = 0; ft < 4; ++ft) {
                int d = ft * 16 + lr;
                bf16x8 bV = *reinterpret_cast<const bf16x8*>(
                    Vl[cur] + d * 128 + (((kc * 4 + lg) ^ (d & 7)) << 4));
                o[ft] = __builtin_amdgcn_mfma_f32_16x16x32_bf16(aP, bV, o[ft], 0, 0, 0);
            }
        }
        __syncthreads();   // drains vmcnt (stage) + syncs buffers
        cur ^= 1;
    }

#pragma unroll
    for (int j = 0; j < 4; ++j) {
        int row = q0 + lg * 4 + j;
        if (row < N_) {
            float inv = 1.f / sr[j];
#pragma unroll
            for (int ft = 0; ft < 4; ++ft) {
                out[((size_t)(b * N_ + row)) * D_ + h * HD_ + ft * 16 + lr] = o[ft][j] * inv;
            }
        }
    }
}

// ---------------------------------------------------------------- launch
extern "C" void kernel_launch(void* const* d_in, const int* in_sizes, int n_in,
                              void* d_out, int out_size, void* d_ws, size_t ws_size,
                              hipStream_t stream)
{
    const float* hs    = (const float*)d_in[0];
    const float* q_w   = (const float*)d_in[1];
    const float* q_b   = (const float*)d_in[2];
    const float* k_w   = (const float*)d_in[3];
    const float* v_w   = (const float*)d_in[4];
    const float* v_b   = (const float*)d_in[5];
    const float* table = (const float*)d_in[6];
    const int*   rpi   = (const int*)d_in[7];
    float* out = (float*)d_out;

    char* ws = (char*)d_ws;
    size_t off = 0;
    auto alloc = [&](size_t bytes) {
        char* p = ws + off;
        off = (off + bytes + 255) & ~(size_t)255;
        return p;
    };
    bf16_t* hb  = (bf16_t*)alloc((size_t)M_ * D_ * 2);
    bf16_t* Wc  = (bf16_t*)alloc((size_t)NW_ * D_ * 2);
    bf16_t* Qb  = (bf16_t*)alloc((size_t)B_ * H_ * N_ * HD_ * 2);
    bf16_t* Kb  = (bf16_t*)alloc((size_t)B_ * H_ * N_ * HD_ * 2);
    size_t vt_bytes = (size_t)B_ * H_ * HD_ * VN_ * 2;
    bf16_t* VTb = (bf16_t*)alloc(vt_bytes);
    float*  bia = (float*)alloc((size_t)H_ * N_ * BPAD_ * 4);

    int n4h = M_ * D_ / 4;
    cvt_f32_bf16<<<(n4h + 255) / 256, 256, 0, stream>>>(hs, hb, n4h);
    int n4w = D_ * D_ / 4;
    cvt_f32_bf16<<<(n4w + 255) / 256, 256, 0, stream>>>(q_w, Wc, n4w);
    cvt_f32_bf16<<<(n4w + 255) / 256, 256, 0, stream>>>(k_w, Wc + (size_t)D_ * D_, n4w);
    cvt_f32_bf16<<<(n4w + 255) / 256, 256, 0, stream>>>(v_w, Wc + (size_t)2 * D_ * D_, n4w);
    hipMemsetAsync(VTb, 0, vt_bytes, stream);
    build_bias_t<<<dim3(N_, H_), 256, 0, stream>>>(table, rpi, bia);

    qkv_gemm<<<dim3((M_ + 127) / 128, NW_ / 128), 256, 0, stream>>>(
        hb, Wc, q_b, v_b, Qb, Kb, VTb);

    attn<<<dim3((N_ + 63) / 64, H_, B_), 256, 0, stream>>>(Qb, Kb, VTb, bia, out);
}

// Round 4
// 375.590 us; speedup vs baseline: 2.2212x; 1.0053x over previous
//
#include <hip/hip_runtime.h>
#include <hip/hip_bf16.h>

#define B_  32
#define N_  577
#define D_  768
#define H_  12
#define HD_ 64
#define M_  (B_ * N_)        // 18464 rows
#define NW_ (3 * D_)         // 2304 fused output cols (q|k|v)
#define VN_ 640              // padded V row stride
#define BPAD_ 580            // bias row-dim padding (mult of 4)
#define SCALE_ 0.18033688f   // 0.125 * log2(e)

typedef __bf16 bf16_t;
typedef __bf16 bf16x8 __attribute__((ext_vector_type(8)));
typedef __bf16 bf16x4 __attribute__((ext_vector_type(4)));
typedef float  f32x4  __attribute__((ext_vector_type(4)));

static __device__ __forceinline__ bf16x8 ldg8(const bf16_t* p) {
    return *reinterpret_cast<const bf16x8*>(p);
}

#define GLOAD_LDS16(g, l)                                                     \
    __builtin_amdgcn_global_load_lds(                                         \
        (const __attribute__((address_space(1))) void*)(g),                   \
        (__attribute__((address_space(3))) void*)(l), 16, 0, 0)

// ---------------------------------------------------------------- fp32->bf16
__global__ void cvt_f32_bf16(const float* __restrict__ src,
                             bf16_t* __restrict__ dst, int n4) {
    int i = blockIdx.x * blockDim.x + threadIdx.x;
    if (i < n4) {
        float4 f = reinterpret_cast<const float4*>(src)[i];
        bf16x4 o;
        o.x = (bf16_t)f.x; o.y = (bf16_t)f.y; o.z = (bf16_t)f.z; o.w = (bf16_t)f.w;
        *reinterpret_cast<bf16x4*>(dst + (size_t)i * 4) = o;
    }
}

// ---------------------------------------------------------------- bias build
// biasT[h][col][row] = table[idx[row][col]*H + h] * log2(e)   (row padded)
__global__ void build_bias_t(const float* __restrict__ table,
                             const int* __restrict__ idx,
                             float* __restrict__ biasT) {
    int col = blockIdx.x;   // key col
    int h   = blockIdx.y;   // head
    for (int row = threadIdx.x; row < BPAD_; row += blockDim.x) {
        int rr = row < N_ ? row : (N_ - 1);
        int id = idx[rr * N_ + col];
        biasT[((size_t)h * N_ + col) * BPAD_ + row] =
            table[id * H_ + h] * 1.44269504f;
    }
}

// ---------------------------------------------------------------- QKV GEMM
// C[M_ x NW_] = hb @ Wcat^T.  128x128 tile, BK=32, double-buffered
// global_load_lds(16B) staging with counted vmcnt (T3+T4), XOR-swizzled
// LDS slots (T2, via pre-swizzled global source -> linear LDS dest).
__global__ __launch_bounds__(256) void qkv_gemm(
    const bf16_t* __restrict__ hb, const bf16_t* __restrict__ W,
    const float* __restrict__ qb, const float* __restrict__ vb,
    bf16_t* __restrict__ Q, bf16_t* __restrict__ K, bf16_t* __restrict__ VT)
{
    __shared__ __align__(16) char ldsA[2][8192];   // [128 rows][4 slots x 16B]
    __shared__ __align__(16) char ldsB[2][8192];

    int tid = threadIdx.x;
    int w  = tid >> 6, l = tid & 63;
    int lr = l & 15, lg = l >> 4;
    int wm = w & 1,  wn = w >> 1;

    int brow = blockIdx.x * 128;
    int bcol = blockIdx.y * 128;

    // staging: chunk = 16 rows (1024B); wave w stages chunks {w, w+4} of A and B.
    // LDS[r][s] holds global slot s ^ ((r>>1)&3)  (slot = 16B = 8 bf16)
    int srow0 = l >> 2;                          // 0..15 within chunk
    int swz   = (l & 3) ^ ((srow0 >> 1) & 3);    // pre-swizzled source slot

    int r0 = w * 16 + srow0;
    int r1 = (w + 4) * 16 + srow0;
    int ga0 = brow + r0; ga0 = ga0 < M_ ? ga0 : (M_ - 1);
    int ga1 = brow + r1; ga1 = ga1 < M_ ? ga1 : (M_ - 1);
    const bf16_t* a0 = hb + (size_t)ga0 * D_ + swz * 8;
    const bf16_t* a1 = hb + (size_t)ga1 * D_ + swz * 8;
    const bf16_t* b0 = W + (size_t)(bcol + r0) * D_ + swz * 8;
    const bf16_t* b1 = W + (size_t)(bcol + r1) * D_ + swz * 8;

    f32x4 acc[4][4] = {};
    const int NT = D_ / 32;   // 24
    int xsw = (lr >> 1) & 3;  // read-side swizzle (same for A and B frags)

    GLOAD_LDS16(a0, ldsA[0] + w * 1024);
    GLOAD_LDS16(b0, ldsB[0] + w * 1024);
    GLOAD_LDS16(a1, ldsA[0] + (w + 4) * 1024);
    GLOAD_LDS16(b1, ldsB[0] + (w + 4) * 1024);

    int cur = 0;
    for (int t = 0; t < NT; ++t) {
        if (t + 1 < NT) {
            int k = (t + 1) * 32;
            GLOAD_LDS16(a0 + k, ldsA[cur ^ 1] + w * 1024);
            GLOAD_LDS16(b0 + k, ldsB[cur ^ 1] + w * 1024);
            GLOAD_LDS16(a1 + k, ldsA[cur ^ 1] + (w + 4) * 1024);
            GLOAD_LDS16(b1 + k, ldsB[cur ^ 1] + (w + 4) * 1024);
            asm volatile("s_waitcnt vmcnt(4)" ::: "memory");   // cur tile landed
        } else {
            asm volatile("s_waitcnt vmcnt(0)" ::: "memory");
        }
        __builtin_amdgcn_s_barrier();
        __builtin_amdgcn_sched_barrier(0);

        const char* pA = ldsA[cur];
        const char* pB = ldsB[cur];
        bf16x8 af[4];
#pragma unroll
        for (int m = 0; m < 4; ++m) {
            int r = wm * 64 + m * 16 + lr;
            af[m] = *reinterpret_cast<const bf16x8*>(
                pA + r * 64 + ((lg ^ xsw) << 4));
        }
#pragma unroll
        for (int n = 0; n < 4; ++n) {
            int r = wn * 64 + n * 16 + lr;
            bf16x8 bfr = *reinterpret_cast<const bf16x8*>(
                pB + r * 64 + ((lg ^ xsw) << 4));
#pragma unroll
            for (int m = 0; m < 4; ++m)
                acc[m][n] = __builtin_amdgcn_mfma_f32_16x16x32_bf16(
                    af[m], bfr, acc[m][n], 0, 0, 0);
        }
        __builtin_amdgcn_sched_barrier(0);
        __builtin_amdgcn_s_barrier();   // WAR: next iter restages this buffer
        cur ^= 1;
    }

    // epilogue: D layout col=lane&15, row=(lane>>4)*4+reg
    int mat = bcol / D_;
    int cb0 = bcol - mat * D_ + wn * 64;
#pragma unroll
    for (int m = 0; m < 4; ++m) {
#pragma unroll
        for (int j = 0; j < 4; ++j) {
            int row = brow + wm * 64 + m * 16 + lg * 4 + j;
            if (row >= M_) continue;
            int bb = row / N_;
            int nn = row - bb * N_;
#pragma unroll
            for (int n = 0; n < 4; ++n) {
                int c  = cb0 + n * 16 + lr;
                int hh = c >> 6, hd = c & 63;
                float v = acc[m][n][j];
                if (mat == 0) {
                    Q[((size_t)(bb * H_ + hh) * N_ + nn) * HD_ + hd] =
                        (bf16_t)(v + qb[c]);
                } else if (mat == 1) {
                    K[((size_t)(bb * H_ + hh) * N_ + nn) * HD_ + hd] = (bf16_t)v;
                } else {
                    VT[((size_t)(bb * H_ + hh) * HD_ + hd) * VN_ + nn] =
                        (bf16_t)(v + vb[c]);
                }
            }
        }
    }
}

// ---------------------------------------------------------------- attention
// 4 waves x 16 q-rows; K,V tiles LDS-staged (XOR-swizzled), double-buffered.
__global__ __launch_bounds__(256) void attn(
    const bf16_t* __restrict__ Q, const bf16_t* __restrict__ K,
    const bf16_t* __restrict__ VT, const float* __restrict__ biasT,
    float* __restrict__ out)
{
    __shared__ __align__(16) char Kl[2][8192];   // [64 key][64 hd] bf16, swz
    __shared__ __align__(16) char Vl[2][8192];   // [64 d][64 key] bf16, swz
    __shared__ __align__(16) char Pl[4][2048];   // per-wave P, swz

    int tid = threadIdx.x;
    int w = tid >> 6, l = tid & 63, lr = l & 15, lg = l >> 4;
    int qt = blockIdx.x, h = blockIdx.y, b = blockIdx.z;

    const bf16_t* Qp = Q  + (size_t)(b * H_ + h) * N_ * HD_;
    const bf16_t* Kp = K  + (size_t)(b * H_ + h) * N_ * HD_;
    const bf16_t* Vp = VT + (size_t)(b * H_ + h) * HD_ * VN_;
    const float*  bp = biasT + (size_t)h * N_ * BPAD_;   // [col][row]

    int q0 = qt * 64 + w * 16;
    int qrow = q0 + lr;
    int qrow_c = qrow < N_ ? qrow : (N_ - 1);
    bf16x8 aQ0 = ldg8(Qp + (size_t)qrow_c * HD_ + lg * 8);
    bf16x8 aQ1 = ldg8(Qp + (size_t)qrow_c * HD_ + 32 + lg * 8);

    int rloc = l >> 3;              // 0..7
    int cswz = (l & 7) ^ rloc;      // swizzled 8-elem column

    f32x4 o[4] = {};
    float mr[4] = {-INFINITY, -INFINITY, -INFINITY, -INFINITY};
    float sr[4] = {0.f, 0.f, 0.f, 0.f};
    char* Pw = Pl[w];

    auto stage = [&](int buf, int k0) {
#pragma unroll
        for (int round = 0; round < 2; ++round) {
            int r = round * 32 + w * 8 + rloc;           // tile row 0..63
            int kr = k0 + r; kr = kr < N_ ? kr : (N_ - 1);
            GLOAD_LDS16(Kp + (size_t)kr * HD_ + cswz * 8,
                        Kl[buf] + round * 4096 + w * 1024);
            GLOAD_LDS16(Vp + (size_t)r * VN_ + k0 + cswz * 8,
                        Vl[buf] + round * 4096 + w * 1024);
        }
    };

    stage(0, 0);
    __syncthreads();

    int cur = 0;
    const int NT = (N_ + 63) / 64;   // 10
    for (int t = 0; t < NT; ++t) {
        int k0 = t * 64;
        if (t + 1 < NT) stage(cur ^ 1, k0 + 64);

        f32x4 s[4];
#pragma unroll
        for (int kt = 0; kt < 4; ++kt) {
            int r = kt * 16 + lr;
            bf16x8 kf0 = *reinterpret_cast<const bf16x8*>(
                Kl[cur] + r * 128 + ((lg ^ (r & 7)) << 4));
            bf16x8 kf1 = *reinterpret_cast<const bf16x8*>(
                Kl[cur] + r * 128 + (((4 + lg) ^ (r & 7)) << 4));
            f32x4 a = {};
            a = __builtin_amdgcn_mfma_f32_16x16x32_bf16(aQ0, kf0, a, 0, 0, 0);
            a = __builtin_amdgcn_mfma_f32_16x16x32_bf16(aQ1, kf1, a, 0, 0, 0);
            s[kt] = a;
        }
#pragma unroll
        for (int kt = 0; kt < 4; ++kt) {
            int col = k0 + kt * 16 + lr;
            bool colv = col < N_;
            int col_c = colv ? col : (N_ - 1);
            f32x4 bb = *reinterpret_cast<const f32x4*>(
                bp + (size_t)col_c * BPAD_ + q0 + lg * 4);
#pragma unroll
            for (int j = 0; j < 4; ++j) {
                float v = s[kt][j] * SCALE_ + bb[j];
                s[kt][j] = colv ? v : -1e30f;
            }
        }
#pragma unroll
        for (int j = 0; j < 4; ++j) {
            float mx = fmaxf(fmaxf(s[0][j], s[1][j]), fmaxf(s[2][j], s[3][j]));
#pragma unroll
            for (int d = 1; d < 16; d <<= 1) mx = fmaxf(mx, __shfl_xor(mx, d));
            float mn = fmaxf(mr[j], mx);
            float sc = __builtin_amdgcn_exp2f(mr[j] - mn);
            mr[j] = mn;
            float rs = 0.f;
#pragma unroll
            for (int kt = 0; kt < 4; ++kt) {
                float p = __builtin_amdgcn_exp2f(s[kt][j] - mn);
                s[kt][j] = p;
                rs += p;
            }
#pragma unroll
            for (int d = 1; d < 16; d <<= 1) rs += __shfl_xor(rs, d);
            sr[j] = sr[j] * sc + rs;
            o[0][j] *= sc; o[1][j] *= sc; o[2][j] *= sc; o[3][j] *= sc;
        }
#pragma unroll
        for (int kt = 0; kt < 4; ++kt) {
#pragma unroll
            for (int j = 0; j < 4; ++j) {
                int row = lg * 4 + j;
                int byte = row * 128 + (kt * 16 + lr) * 2;
                byte ^= (row & 7) << 4;
                *reinterpret_cast<bf16_t*>(Pw + byte) = (bf16_t)s[kt][j];
            }
        }
#pragma unroll
        for (int kc = 0; kc < 2; ++kc) {
            int pbyte = lr * 128 + kc * 64 + lg * 16;
            pbyte ^= (lr & 7) << 4;
            bf16x8 aP = *reinterpret_cast<const bf16x8*>(Pw + pbyte);
#pragma unroll
            for (int ft = 0; ft < 4; ++ft) {
                int d = ft * 16 + lr;
                bf16x8 bV = *reinterpret_cast<const bf16x8*>(
                    Vl[cur] + d * 128 + (((kc * 4 + lg) ^ (d & 7)) << 4));
                o[ft] = __builtin_amdgcn_mfma_f32_16x16x32_bf16(aP, bV, o[ft], 0, 0, 0);
            }
        }
        __syncthreads();   // drains vmcnt (stage) + syncs buffers
        cur ^= 1;
    }

#pragma unroll
    for (int j = 0; j < 4; ++j) {
        int row = q0 + lg * 4 + j;
        if (row < N_) {
            float inv = 1.f / sr[j];
#pragma unroll
            for (int ft = 0; ft < 4; ++ft) {
                out[((size_t)(b * N_ + row)) * D_ + h * HD_ + ft * 16 + lr] = o[ft][j] * inv;
            }
        }
    }
}

// ---------------------------------------------------------------- launch
extern "C" void kernel_launch(void* const* d_in, const int* in_sizes, int n_in,
                              void* d_out, int out_size, void* d_ws, size_t ws_size,
                              hipStream_t stream)
{
    const float* hs    = (const float*)d_in[0];
    const float* q_w   = (const float*)d_in[1];
    const float* q_b   = (const float*)d_in[2];
    const float* k_w   = (const float*)d_in[3];
    const float* v_w   = (const float*)d_in[4];
    const float* v_b   = (const float*)d_in[5];
    const float* table = (const float*)d_in[6];
    const int*   rpi   = (const int*)d_in[7];
    float* out = (float*)d_out;

    char* ws = (char*)d_ws;
    size_t off = 0;
    auto alloc = [&](size_t bytes) {
        char* p = ws + off;
        off = (off + bytes + 255) & ~(size_t)255;
        return p;
    };
    bf16_t* hb  = (bf16_t*)alloc((size_t)M_ * D_ * 2);
    bf16_t* Wc  = (bf16_t*)alloc((size_t)NW_ * D_ * 2);
    bf16_t* Qb  = (bf16_t*)alloc((size_t)B_ * H_ * N_ * HD_ * 2);
    bf16_t* Kb  = (bf16_t*)alloc((size_t)B_ * H_ * N_ * HD_ * 2);
    size_t vt_bytes = (size_t)B_ * H_ * HD_ * VN_ * 2;
    bf16_t* VTb = (bf16_t*)alloc(vt_bytes);
    float*  bia = (float*)alloc((size_t)H_ * N_ * BPAD_ * 4);

    int n4h = M_ * D_ / 4;
    cvt_f32_bf16<<<(n4h + 255) / 256, 256, 0, stream>>>(hs, hb, n4h);
    int n4w = D_ * D_ / 4;
    cvt_f32_bf16<<<(n4w + 255) / 256, 256, 0, stream>>>(q_w, Wc, n4w);
    cvt_f32_bf16<<<(n4w + 255) / 256, 256, 0, stream>>>(k_w, Wc + (size_t)D_ * D_, n4w);
    cvt_f32_bf16<<<(n4w + 255) / 256, 256, 0, stream>>>(v_w, Wc + (size_t)2 * D_ * D_, n4w);
    hipMemsetAsync(VTb, 0, vt_bytes, stream);
    build_bias_t<<<dim3(N_, H_), 256, 0, stream>>>(table, rpi, bia);

    qkv_gemm<<<dim3((M_ + 127) / 128, NW_ / 128), 256, 0, stream>>>(
        hb, Wc, q_b, v_b, Qb, Kb, VTb);

    attn<<<dim3((N_ + 63) / 64, H_, B_), 256, 0, stream>>>(Qb, Kb, VTb, bia, out);
}

// Round 5
// 271.978 us; speedup vs baseline: 3.0674x; 1.3810x over previous
//
#include <hip/hip_runtime.h>
#include <hip/hip_bf16.h>

#define B_  32
#define N_  577
#define D_  768
#define H_  12
#define HD_ 64
#define M_  (B_ * N_)        // 18464 rows
#define NW_ (3 * D_)         // 2304 fused output cols (q|k|v)
#define VN_ 640              // padded V row stride
#define BPAD_ 580            // bias row-dim padding (mult of 4)
#define SCALE_ 0.18033688f   // 0.125 * log2(e)

typedef __bf16 bf16_t;
typedef __bf16 bf16x8 __attribute__((ext_vector_type(8)));
typedef __bf16 bf16x4 __attribute__((ext_vector_type(4)));
typedef float  f32x4  __attribute__((ext_vector_type(4)));

static __device__ __forceinline__ bf16x8 ldg8(const bf16_t* p) {
    return *reinterpret_cast<const bf16x8*>(p);
}

#define GLOAD_LDS16(g, l)                                                     \
    __builtin_amdgcn_global_load_lds(                                         \
        (const __attribute__((address_space(1))) void*)(g),                   \
        (__attribute__((address_space(3))) void*)(l), 16, 0, 0)

// ---------------------------------------------------------------- fp32->bf16
__global__ void cvt_f32_bf16(const float* __restrict__ src,
                             bf16_t* __restrict__ dst, int n4) {
    int i = blockIdx.x * blockDim.x + threadIdx.x;
    if (i < n4) {
        float4 f = reinterpret_cast<const float4*>(src)[i];
        bf16x4 o;
        o.x = (bf16_t)f.x; o.y = (bf16_t)f.y; o.z = (bf16_t)f.z; o.w = (bf16_t)f.w;
        *reinterpret_cast<bf16x4*>(dst + (size_t)i * 4) = o;
    }
}

// ---------------------------------------------------------------- bias build
// biasT[h][col][row] = table[idx[row][col]*H + h] * log2(e)   (row padded)
__global__ void build_bias_t(const float* __restrict__ table,
                             const int* __restrict__ idx,
                             float* __restrict__ biasT) {
    int col = blockIdx.x;   // key col
    int h   = blockIdx.y;   // head
    for (int row = threadIdx.x; row < BPAD_; row += blockDim.x) {
        int rr = row < N_ ? row : (N_ - 1);
        int id = idx[rr * N_ + col];
        biasT[((size_t)h * N_ + col) * BPAD_ + row] =
            table[id * H_ + h] * 1.44269504f;
    }
}

// ---------------------------------------------------------------- QKV GEMM
// C[M_ x NW_] = hb @ Wcat^T.  128x128 tile, BK=64, double-buffered staging
// with counted vmcnt; XOR-swizzled LDS slots (linear dest, pre-swz source);
// XCD-chunked y-fast grid; coalesced LDS-repack epilogue.
__global__ __launch_bounds__(256) void qkv_gemm(
    const bf16_t* __restrict__ hb, const bf16_t* __restrict__ W,
    const float* __restrict__ qb, const float* __restrict__ vb,
    bf16_t* __restrict__ Q, bf16_t* __restrict__ K, bf16_t* __restrict__ VT)
{
    __shared__ __align__(16) char lds[65536];  // A:[2][16K] @0, B:[2][16K] @32K

    int tid = threadIdx.x;
    int w  = tid >> 6, l = tid & 63;
    int lr = l & 15, lg = l >> 4;
    int wm = w & 1,  wn = w >> 1;

    // grid decode: bijective XCD chunk (nwg=2610) + y-fast within chunk
    int wg = blockIdx.x;
    int xcd = wg & 7, pos = wg >> 3;
    const int Q8 = 2610 / 8, R8 = 2610 % 8;   // 326, 2
    int base = xcd < R8 ? xcd * (Q8 + 1) : R8 * (Q8 + 1) + (xcd - R8) * Q8;
    int wgid = base + pos;
    int bx = wgid / 18, y = wgid - bx * 18;
    int brow = bx * 128;
    int mat = y / 6, ysub = y - mat * 6;      // matrix 0/1/2, 128-col tile in it
    int cbase = ysub * 128;                   // col offset within matrix

    // staging: idx = r*256+tid -> row=idx>>3 (128B rows), slot=idx&7 (16B)
    // LDS[row][p] = G[row][p ^ (row&7)]
    int srow = tid >> 3;                      // 0..31 (+r*32)
    int sslot = (tid & 7) ^ (srow & 7);
    const bf16_t* pa[4];
    const bf16_t* pb[4];
#pragma unroll
    for (int r = 0; r < 4; ++r) {
        int ra = brow + r * 32 + srow; ra = ra < M_ ? ra : (M_ - 1);
        pa[r] = hb + (size_t)ra * D_ + sslot * 8;
        pb[r] = W + (size_t)(y * 128 + r * 32 + srow) * D_ + sslot * 8;
    }

    auto stage = [&](int buf, int k) {
#pragma unroll
        for (int r = 0; r < 4; ++r) {
            GLOAD_LDS16(pa[r] + k, lds + buf * 16384 + r * 4096 + tid * 16);
            GLOAD_LDS16(pb[r] + k, lds + 32768 + buf * 16384 + r * 4096 + tid * 16);
        }
    };

    f32x4 acc[4][4] = {};
    stage(0, 0);
    int cur = 0;
    for (int t = 0; t < 12; ++t) {
        if (t < 11) {
            stage(cur ^ 1, (t + 1) * 64);
            asm volatile("s_waitcnt vmcnt(8)" ::: "memory");  // tile t landed
        } else {
            asm volatile("s_waitcnt vmcnt(0)" ::: "memory");
        }
        __builtin_amdgcn_s_barrier();
        __builtin_amdgcn_sched_barrier(0);

        const char* pA = lds + cur * 16384;
        const char* pB = lds + 32768 + cur * 16384;
#pragma unroll
        for (int kk = 0; kk < 2; ++kk) {
            bf16x8 af[4];
#pragma unroll
            for (int m = 0; m < 4; ++m) {
                int row = wm * 64 + m * 16 + lr;
                af[m] = *reinterpret_cast<const bf16x8*>(
                    pA + row * 128 + (((kk * 4 + lg) ^ (lr & 7)) << 4));
            }
#pragma unroll
            for (int n = 0; n < 4; ++n) {
                int row = wn * 64 + n * 16 + lr;
                bf16x8 bfr = *reinterpret_cast<const bf16x8*>(
                    pB + row * 128 + (((kk * 4 + lg) ^ (lr & 7)) << 4));
#pragma unroll
                for (int m = 0; m < 4; ++m)
                    acc[m][n] = __builtin_amdgcn_mfma_f32_16x16x32_bf16(
                        af[m], bfr, acc[m][n], 0, 0, 0);
            }
        }
        __builtin_amdgcn_sched_barrier(0);
        __builtin_amdgcn_s_barrier();   // WAR: next iter restages this buffer
        cur ^= 1;
    }

    // ---- epilogue: acc -> LDS repack (stride 132 bf16 = 264B), then
    // coalesced 16B global stores.  D-frag: col=lr (per n), row=lg*4+j (per m).
    bf16_t* ep = (bf16_t*)lds;
    if (mat < 2) {
#pragma unroll
        for (int m = 0; m < 4; ++m)
#pragma unroll
            for (int n = 0; n < 4; ++n) {
                int col = wn * 64 + n * 16 + lr;
                float badd = (mat == 0) ? qb[cbase + col] : 0.f;
#pragma unroll
                for (int j = 0; j < 4; ++j) {
                    int row = wm * 64 + m * 16 + lg * 4 + j;
                    ep[row * 132 + col] = (bf16_t)(acc[m][n][j] + badd);
                }
            }
        __syncthreads();
        bf16_t* dst0 = (mat == 0) ? Q : K;
#pragma unroll
        for (int k = 0; k < 8; ++k) {
            int c = k * 256 + tid;            // 0..2047
            int row = c >> 4, cc = c & 15;
            int grow = brow + row;
            if (grow < M_) {
                int bb = grow / N_, nn = grow - bb * N_;
                int col0 = cc * 8;
                int hh = ysub * 2 + (col0 >> 6);
                int hd0 = col0 & 63;
                bf16x8 vc = *reinterpret_cast<const bf16x8*>(ep + row * 132 + col0);
                *reinterpret_cast<bf16x8*>(
                    dst0 + ((size_t)(bb * H_ + hh) * N_ + nn) * HD_ + hd0) = vc;
            }
        }
    } else {
        // VT: transpose via LDS  ep[col*132 + row]
#pragma unroll
        for (int m = 0; m < 4; ++m)
#pragma unroll
            for (int n = 0; n < 4; ++n) {
                int col = wn * 64 + n * 16 + lr;
                float badd = vb[cbase + col];
#pragma unroll
                for (int j = 0; j < 4; ++j) {
                    int row = wm * 64 + m * 16 + lg * 4 + j;
                    ep[col * 132 + row] = (bf16_t)(acc[m][n][j] + badd);
                }
            }
        __syncthreads();
#pragma unroll
        for (int k = 0; k < 8; ++k) {
            int c = k * 256 + tid;
            int col = c >> 4, rc = c & 15;
            int grow0 = brow + rc * 8;
            int hh = ysub * 2 + (col >> 6), hd = col & 63;
            int bb = grow0 / N_, nn0 = grow0 - bb * N_;
            if (nn0 + 8 <= N_ && grow0 + 8 <= M_) {
                *reinterpret_cast<bf16x8*>(
                    VT + ((size_t)(bb * H_ + hh) * HD_ + hd) * VN_ + nn0) =
                    *reinterpret_cast<const bf16x8*>(ep + col * 132 + rc * 8);
            } else {
                for (int jj = 0; jj < 8; ++jj) {
                    int grow = grow0 + jj;
                    if (grow >= M_) break;
                    int b2 = grow / N_, n2 = grow - b2 * N_;
                    VT[((size_t)(b2 * H_ + hh) * HD_ + hd) * VN_ + n2] =
                        ep[col * 132 + rc * 8 + jj];
                }
            }
        }
    }
}

// ---------------------------------------------------------------- attention
// 4 waves x 16 q-rows; K,V tiles LDS-staged (XOR-swizzled), double-buffered.
// Grid: 1D, XCD-chunked with h slowest (bias-plane L2 locality).
__global__ __launch_bounds__(256) void attn(
    const bf16_t* __restrict__ Q, const bf16_t* __restrict__ K,
    const bf16_t* __restrict__ VT, const float* __restrict__ biasT,
    float* __restrict__ out)
{
    __shared__ __align__(16) char Kl[2][8192];   // [64 key][64 hd] bf16, swz
    __shared__ __align__(16) char Vl[2][8192];   // [64 d][64 key] bf16, swz
    __shared__ __align__(16) char Pl[4][2048];   // per-wave P, swz

    int tid = threadIdx.x;
    int w = tid >> 6, l = tid & 63, lr = l & 15, lg = l >> 4;

    // grid decode: 3840 blocks, 480/XCD; within chunk: qt fastest, b, then h
    int wg = blockIdx.x;
    int wgid = (wg & 7) * 480 + (wg >> 3);
    int h = wgid / 320;
    int rem = wgid - h * 320;
    int b = rem / 10;
    int qt = rem - b * 10;

    const bf16_t* Qp = Q  + (size_t)(b * H_ + h) * N_ * HD_;
    const bf16_t* Kp = K  + (size_t)(b * H_ + h) * N_ * HD_;
    const bf16_t* Vp = VT + (size_t)(b * H_ + h) * HD_ * VN_;
    const float*  bp = biasT + (size_t)h * N_ * BPAD_;   // [col][row]

    int q0 = qt * 64 + w * 16;
    int qrow = q0 + lr;
    int qrow_c = qrow < N_ ? qrow : (N_ - 1);
    bf16x8 aQ0 = ldg8(Qp + (size_t)qrow_c * HD_ + lg * 8);
    bf16x8 aQ1 = ldg8(Qp + (size_t)qrow_c * HD_ + 32 + lg * 8);

    int rloc = l >> 3;              // 0..7
    int cswz = (l & 7) ^ rloc;      // swizzled 8-elem column

    f32x4 o[4] = {};
    float mr[4] = {-INFINITY, -INFINITY, -INFINITY, -INFINITY};
    float sr[4] = {0.f, 0.f, 0.f, 0.f};
    char* Pw = Pl[w];

    auto stage = [&](int buf, int k0) {
#pragma unroll
        for (int round = 0; round < 2; ++round) {
            int r = round * 32 + w * 8 + rloc;           // tile row 0..63
            int kr = k0 + r; kr = kr < N_ ? kr : (N_ - 1);
            GLOAD_LDS16(Kp + (size_t)kr * HD_ + cswz * 8,
                        Kl[buf] + round * 4096 + w * 1024);
            GLOAD_LDS16(Vp + (size_t)r * VN_ + k0 + cswz * 8,
                        Vl[buf] + round * 4096 + w * 1024);
        }
    };

    stage(0, 0);
    __syncthreads();

    int cur = 0;
    const int NT = (N_ + 63) / 64;   // 10
    for (int t = 0; t < NT; ++t) {
        int k0 = t * 64;
        if (t + 1 < NT) stage(cur ^ 1, k0 + 64);

        f32x4 s[4];
#pragma unroll
        for (int kt = 0; kt < 4; ++kt) {
            int r = kt * 16 + lr;
            bf16x8 kf0 = *reinterpret_cast<const bf16x8*>(
                Kl[cur] + r * 128 + ((lg ^ (r & 7)) << 4));
            bf16x8 kf1 = *reinterpret_cast<const bf16x8*>(
                Kl[cur] + r * 128 + (((4 + lg) ^ (r & 7)) << 4));
            f32x4 a = {};
            a = __builtin_amdgcn_mfma_f32_16x16x32_bf16(aQ0, kf0, a, 0, 0, 0);
            a = __builtin_amdgcn_mfma_f32_16x16x32_bf16(aQ1, kf1, a, 0, 0, 0);
            s[kt] = a;
        }
#pragma unroll
        for (int kt = 0; kt < 4; ++kt) {
            int col = k0 + kt * 16 + lr;
            bool colv = col < N_;
            int col_c = colv ? col : (N_ - 1);
            f32x4 bb = *reinterpret_cast<const f32x4*>(
                bp + (size_t)col_c * BPAD_ + q0 + lg * 4);
#pragma unroll
            for (int j = 0; j < 4; ++j) {
                float v = s[kt][j] * SCALE_ + bb[j];
                s[kt][j] = colv ? v : -1e30f;
            }
        }
#pragma unroll
        for (int j = 0; j < 4; ++j) {
            float mx = fmaxf(fmaxf(s[0][j], s[1][j]), fmaxf(s[2][j], s[3][j]));
#pragma unroll
            for (int d = 1; d < 16; d <<= 1) mx = fmaxf(mx, __shfl_xor(mx, d));
            float mn = fmaxf(mr[j], mx);
            float sc = __builtin_amdgcn_exp2f(mr[j] - mn);
            mr[j] = mn;
            float rs = 0.f;
#pragma unroll
            for (int kt = 0; kt < 4; ++kt) {
                float p = __builtin_amdgcn_exp2f(s[kt][j] - mn);
                s[kt][j] = p;
                rs += p;
            }
#pragma unroll
            for (int d = 1; d < 16; d <<= 1) rs += __shfl_xor(rs, d);
            sr[j] = sr[j] * sc + rs;
            o[0][j] *= sc; o[1][j] *= sc; o[2][j] *= sc; o[3][j] *= sc;
        }
#pragma unroll
        for (int kt = 0; kt < 4; ++kt) {
#pragma unroll
            for (int j = 0; j < 4; ++j) {
                int row = lg * 4 + j;
                int byte = row * 128 + (kt * 16 + lr) * 2;
                byte ^= (row & 7) << 4;
                *reinterpret_cast<bf16_t*>(Pw + byte) = (bf16_t)s[kt][j];
            }
        }
#pragma unroll
        for (int kc = 0; kc < 2; ++kc) {
            int pbyte = lr * 128 + kc * 64 + lg * 16;
            pbyte ^= (lr & 7) << 4;
            bf16x8 aP = *reinterpret_cast<const bf16x8*>(Pw + pbyte);
#pragma unroll
            for (int ft = 0; ft < 4; ++ft) {
                int d = ft * 16 + lr;
                bf16x8 bV = *reinterpret_cast<const bf16x8*>(
                    Vl[cur] + d * 128 + (((kc * 4 + lg) ^ (d & 7)) << 4));
                o[ft] = __builtin_amdgcn_mfma_f32_16x16x32_bf16(aP, bV, o[ft], 0, 0, 0);
            }
        }
        __syncthreads();   // drains vmcnt (stage) + syncs buffers
        cur ^= 1;
    }

#pragma unroll
    for (int j = 0; j < 4; ++j) {
        int row = q0 + lg * 4 + j;
        if (row < N_) {
            float inv = 1.f / sr[j];
#pragma unroll
            for (int ft = 0; ft < 4; ++ft) {
                out[((size_t)(b * N_ + row)) * D_ + h * HD_ + ft * 16 + lr] = o[ft][j] * inv;
            }
        }
    }
}

// ---------------------------------------------------------------- launch
extern "C" void kernel_launch(void* const* d_in, const int* in_sizes, int n_in,
                              void* d_out, int out_size, void* d_ws, size_t ws_size,
                              hipStream_t stream)
{
    const float* hs    = (const float*)d_in[0];
    const float* q_w   = (const float*)d_in[1];
    const float* q_b   = (const float*)d_in[2];
    const float* k_w   = (const float*)d_in[3];
    const float* v_w   = (const float*)d_in[4];
    const float* v_b   = (const float*)d_in[5];
    const float* table = (const float*)d_in[6];
    const int*   rpi   = (const int*)d_in[7];
    float* out = (float*)d_out;

    char* ws = (char*)d_ws;
    size_t off = 0;
    auto alloc = [&](size_t bytes) {
        char* p = ws + off;
        off = (off + bytes + 255) & ~(size_t)255;
        return p;
    };
    bf16_t* hb  = (bf16_t*)alloc((size_t)M_ * D_ * 2);
    bf16_t* Wc  = (bf16_t*)alloc((size_t)NW_ * D_ * 2);
    bf16_t* Qb  = (bf16_t*)alloc((size_t)B_ * H_ * N_ * HD_ * 2);
    bf16_t* Kb  = (bf16_t*)alloc((size_t)B_ * H_ * N_ * HD_ * 2);
    bf16_t* VTb = (bf16_t*)alloc((size_t)B_ * H_ * HD_ * VN_ * 2);
    float*  bia = (float*)alloc((size_t)H_ * N_ * BPAD_ * 4);
    // note: VT pad cols [577,640) never written; stay 0xAA = -3e-13 bf16,
    // multiplied by exactly-zero P for masked keys -> no output effect.

    int n4h = M_ * D_ / 4;
    cvt_f32_bf16<<<(n4h + 255) / 256, 256, 0, stream>>>(hs, hb, n4h);
    int n4w = D_ * D_ / 4;
    cvt_f32_bf16<<<(n4w + 255) / 256, 256, 0, stream>>>(q_w, Wc, n4w);
    cvt_f32_bf16<<<(n4w + 255) / 256, 256, 0, stream>>>(k_w, Wc + (size_t)D_ * D_, n4w);
    cvt_f32_bf16<<<(n4w + 255) / 256, 256, 0, stream>>>(v_w, Wc + (size_t)2 * D_ * D_, n4w);
    build_bias_t<<<dim3(N_, H_), 256, 0, stream>>>(table, rpi, bia);

    qkv_gemm<<<2610, 256, 0, stream>>>(hb, Wc, q_b, v_b, Qb, Kb, VTb);

    attn<<<3840, 256, 0, stream>>>(Qb, Kb, VTb, bia, out);
}

// Round 6
// 267.159 us; speedup vs baseline: 3.1227x; 1.0180x over previous
//
#include <hip/hip_runtime.h>
#include <hip/hip_bf16.h>

#define B_  32
#define N_  577
#define D_  768
#define H_  12
#define HD_ 64
#define M_  (B_ * N_)        // 18464 rows
#define NW_ (3 * D_)         // 2304 fused output cols (q|k|v)
#define VN_ 640              // padded V row stride
#define BPAD_ 580            // bias row-dim padding (mult of 4)
#define SCALE_ 0.18033688f   // 0.125 * log2(e)

typedef __bf16 bf16_t;
typedef __bf16 bf16x8 __attribute__((ext_vector_type(8)));
typedef __bf16 bf16x4 __attribute__((ext_vector_type(4)));
typedef float  f32x4  __attribute__((ext_vector_type(4)));

static __device__ __forceinline__ bf16x8 ldg8(const bf16_t* p) {
    return *reinterpret_cast<const bf16x8*>(p);
}

#define GLOAD_LDS16(g, l)                                                     \
    __builtin_amdgcn_global_load_lds(                                         \
        (const __attribute__((address_space(1))) void*)(g),                   \
        (__attribute__((address_space(3))) void*)(l), 16, 0, 0)

// ---------------------------------------------------------------- fp32->bf16
__global__ void cvt_f32_bf16(const float* __restrict__ src,
                             bf16_t* __restrict__ dst, int n4) {
    int i = blockIdx.x * blockDim.x + threadIdx.x;
    if (i < n4) {
        float4 f = reinterpret_cast<const float4*>(src)[i];
        bf16x4 o;
        o.x = (bf16_t)f.x; o.y = (bf16_t)f.y; o.z = (bf16_t)f.z; o.w = (bf16_t)f.w;
        *reinterpret_cast<bf16x4*>(dst + (size_t)i * 4) = o;
    }
}

// three weight matrices in one launch (blockIdx.y selects)
__global__ void cvt3_f32_bf16(const float* __restrict__ s0,
                              const float* __restrict__ s1,
                              const float* __restrict__ s2,
                              bf16_t* __restrict__ dst, int n4) {
    int i = blockIdx.x * blockDim.x + threadIdx.x;
    if (i < n4) {
        const float* src = blockIdx.y == 0 ? s0 : (blockIdx.y == 1 ? s1 : s2);
        float4 f = reinterpret_cast<const float4*>(src)[i];
        bf16x4 o;
        o.x = (bf16_t)f.x; o.y = (bf16_t)f.y; o.z = (bf16_t)f.z; o.w = (bf16_t)f.w;
        *reinterpret_cast<bf16x4*>(dst + (size_t)blockIdx.y * n4 * 4 + (size_t)i * 4) = o;
    }
}

// ---------------------------------------------------------------- bias build
// biasT[h][col][row] = table[idx[row][col]*H + h] * log2(e)   (row padded)
__global__ void build_bias_t(const float* __restrict__ table,
                             const int* __restrict__ idx,
                             float* __restrict__ biasT) {
    int col = blockIdx.x;   // key col
    int h   = blockIdx.y;   // head
    for (int row = threadIdx.x; row < BPAD_; row += blockDim.x) {
        int rr = row < N_ ? row : (N_ - 1);
        int id = idx[rr * N_ + col];
        biasT[((size_t)h * N_ + col) * BPAD_ + row] =
            table[id * H_ + h] * 1.44269504f;
    }
}

// ---------------------------------------------------------------- QKV GEMM
__global__ __launch_bounds__(256) void qkv_gemm(
    const bf16_t* __restrict__ hb, const bf16_t* __restrict__ W,
    const float* __restrict__ qb, const float* __restrict__ vb,
    bf16_t* __restrict__ Q, bf16_t* __restrict__ K, bf16_t* __restrict__ VT)
{
    __shared__ __align__(16) char lds[65536];  // A:[2][16K] @0, B:[2][16K] @32K

    int tid = threadIdx.x;
    int w  = tid >> 6, l = tid & 63;
    int lr = l & 15, lg = l >> 4;
    int wm = w & 1,  wn = w >> 1;

    int wg = blockIdx.x;
    int xcd = wg & 7, pos = wg >> 3;
    const int Q8 = 2610 / 8, R8 = 2610 % 8;   // 326, 2
    int base = xcd < R8 ? xcd * (Q8 + 1) : R8 * (Q8 + 1) + (xcd - R8) * Q8;
    int wgid = base + pos;
    int bx = wgid / 18, y = wgid - bx * 18;
    int brow = bx * 128;
    int mat = y / 6, ysub = y - mat * 6;
    int cbase = ysub * 128;

    int srow = tid >> 3;
    int sslot = (tid & 7) ^ (srow & 7);
    const bf16_t* pa[4];
    const bf16_t* pb[4];
#pragma unroll
    for (int r = 0; r < 4; ++r) {
        int ra = brow + r * 32 + srow; ra = ra < M_ ? ra : (M_ - 1);
        pa[r] = hb + (size_t)ra * D_ + sslot * 8;
        pb[r] = W + (size_t)(y * 128 + r * 32 + srow) * D_ + sslot * 8;
    }

    auto stage = [&](int buf, int k) {
#pragma unroll
        for (int r = 0; r < 4; ++r) {
            GLOAD_LDS16(pa[r] + k, lds + buf * 16384 + r * 4096 + tid * 16);
            GLOAD_LDS16(pb[r] + k, lds + 32768 + buf * 16384 + r * 4096 + tid * 16);
        }
    };

    f32x4 acc[4][4] = {};
    stage(0, 0);
    int cur = 0;
    for (int t = 0; t < 12; ++t) {
        if (t < 11) {
            stage(cur ^ 1, (t + 1) * 64);
            asm volatile("s_waitcnt vmcnt(8)" ::: "memory");
        } else {
            asm volatile("s_waitcnt vmcnt(0)" ::: "memory");
        }
        __builtin_amdgcn_s_barrier();
        __builtin_amdgcn_sched_barrier(0);

        const char* pA = lds + cur * 16384;
        const char* pB = lds + 32768 + cur * 16384;
#pragma unroll
        for (int kk = 0; kk < 2; ++kk) {
            bf16x8 af[4];
#pragma unroll
            for (int m = 0; m < 4; ++m) {
                int row = wm * 64 + m * 16 + lr;
                af[m] = *reinterpret_cast<const bf16x8*>(
                    pA + row * 128 + (((kk * 4 + lg) ^ (lr & 7)) << 4));
            }
#pragma unroll
            for (int n = 0; n < 4; ++n) {
                int row = wn * 64 + n * 16 + lr;
                bf16x8 bfr = *reinterpret_cast<const bf16x8*>(
                    pB + row * 128 + (((kk * 4 + lg) ^ (lr & 7)) << 4));
#pragma unroll
                for (int m = 0; m < 4; ++m)
                    acc[m][n] = __builtin_amdgcn_mfma_f32_16x16x32_bf16(
                        af[m], bfr, acc[m][n], 0, 0, 0);
            }
        }
        __builtin_amdgcn_sched_barrier(0);
        __builtin_amdgcn_s_barrier();
        cur ^= 1;
    }

    bf16_t* ep = (bf16_t*)lds;
    if (mat < 2) {
#pragma unroll
        for (int m = 0; m < 4; ++m)
#pragma unroll
            for (int n = 0; n < 4; ++n) {
                int col = wn * 64 + n * 16 + lr;
                float badd = (mat == 0) ? qb[cbase + col] : 0.f;
#pragma unroll
                for (int j = 0; j < 4; ++j) {
                    int row = wm * 64 + m * 16 + lg * 4 + j;
                    ep[row * 132 + col] = (bf16_t)(acc[m][n][j] + badd);
                }
            }
        __syncthreads();
        bf16_t* dst0 = (mat == 0) ? Q : K;
#pragma unroll
        for (int k = 0; k < 8; ++k) {
            int c = k * 256 + tid;
            int row = c >> 4, cc = c & 15;
            int grow = brow + row;
            if (grow < M_) {
                int bb = grow / N_, nn = grow - bb * N_;
                int col0 = cc * 8;
                int hh = ysub * 2 + (col0 >> 6);
                int hd0 = col0 & 63;
                bf16x8 vc = *reinterpret_cast<const bf16x8*>(ep + row * 132 + col0);
                *reinterpret_cast<bf16x8*>(
                    dst0 + ((size_t)(bb * H_ + hh) * N_ + nn) * HD_ + hd0) = vc;
            }
        }
    } else {
#pragma unroll
        for (int m = 0; m < 4; ++m)
#pragma unroll
            for (int n = 0; n < 4; ++n) {
                int col = wn * 64 + n * 16 + lr;
                float badd = vb[cbase + col];
#pragma unroll
                for (int j = 0; j < 4; ++j) {
                    int row = wm * 64 + m * 16 + lg * 4 + j;
                    ep[col * 132 + row] = (bf16_t)(acc[m][n][j] + badd);
                }
            }
        __syncthreads();
#pragma unroll
        for (int k = 0; k < 8; ++k) {
            int c = k * 256 + tid;
            int col = c >> 4, rc = c & 15;
            int grow0 = brow + rc * 8;
            int hh = ysub * 2 + (col >> 6), hd = col & 63;
            int bb = grow0 / N_, nn0 = grow0 - bb * N_;
            if (nn0 + 8 <= N_ && grow0 + 8 <= M_) {
                *reinterpret_cast<bf16x8*>(
                    VT + ((size_t)(bb * H_ + hh) * HD_ + hd) * VN_ + nn0) =
                    *reinterpret_cast<const bf16x8*>(ep + col * 132 + rc * 8);
            } else {
                for (int jj = 0; jj < 8; ++jj) {
                    int grow = grow0 + jj;
                    if (grow >= M_) break;
                    int b2 = grow / N_, n2 = grow - b2 * N_;
                    VT[((size_t)(b2 * H_ + hh) * HD_ + hd) * VN_ + n2] =
                        ep[col * 132 + rc * 8 + jj];
                }
            }
        }
    }
}

// ---------------------------------------------------------------- attention
// 4 waves x 16 q-rows; K double-buffered, V single-buffered (staged at top,
// used after counted vmcnt(2) + raw barrier); setprio around MFMA; defer-max.
__global__ __launch_bounds__(256) void attn(
    const bf16_t* __restrict__ Q, const bf16_t* __restrict__ K,
    const bf16_t* __restrict__ VT, const float* __restrict__ biasT,
    float* __restrict__ out)
{
    __shared__ __align__(16) char Kl[2][8192];   // [64 key][64 hd] bf16, swz
    __shared__ __align__(16) char Vl[8192];      // [64 d][64 key] bf16, swz
    __shared__ __align__(16) char Pl[4][2048];   // per-wave P, swz
    // total 32768 -> 5 blocks/CU

    int tid = threadIdx.x;
    int w = tid >> 6, l = tid & 63, lr = l & 15, lg = l >> 4;

    int wg = blockIdx.x;
    int wgid = (wg & 7) * 480 + (wg >> 3);
    int h = wgid / 320;
    int rem = wgid - h * 320;
    int b = rem / 10;
    int qt = rem - b * 10;

    const bf16_t* Qp = Q  + (size_t)(b * H_ + h) * N_ * HD_;
    const bf16_t* Kp = K  + (size_t)(b * H_ + h) * N_ * HD_;
    const bf16_t* Vp = VT + (size_t)(b * H_ + h) * HD_ * VN_;
    const float*  bp = biasT + (size_t)h * N_ * BPAD_;   // [col][row]

    int q0 = qt * 64 + w * 16;
    int qrow = q0 + lr;
    int qrow_c = qrow < N_ ? qrow : (N_ - 1);
    bf16x8 aQ0 = ldg8(Qp + (size_t)qrow_c * HD_ + lg * 8);
    bf16x8 aQ1 = ldg8(Qp + (size_t)qrow_c * HD_ + 32 + lg * 8);

    int rloc = l >> 3;              // 0..7
    int cswz = (l & 7) ^ rloc;      // swizzled 8-elem column

    f32x4 o[4] = {};
    float mr[4] = {-INFINITY, -INFINITY, -INFINITY, -INFINITY};
    float sr[4] = {0.f, 0.f, 0.f, 0.f};
    char* Pw = Pl[w];

    auto stageK = [&](int buf, int k0) {
#pragma unroll
        for (int round = 0; round < 2; ++round) {
            int r = round * 32 + w * 8 + rloc;
            int kr = k0 + r; kr = kr < N_ ? kr : (N_ - 1);
            GLOAD_LDS16(Kp + (size_t)kr * HD_ + cswz * 8,
                        Kl[buf] + round * 4096 + w * 1024);
        }
    };
    auto stageV = [&](int k0) {
#pragma unroll
        for (int round = 0; round < 2; ++round) {
            int r = round * 32 + w * 8 + rloc;
            GLOAD_LDS16(Vp + (size_t)r * VN_ + k0 + cswz * 8,
                        Vl + round * 4096 + w * 1024);
        }
    };

    stageK(0, 0);
    __syncthreads();

    int cur = 0;
    const int NT = (N_ + 63) / 64;   // 10
    for (int t = 0; t < NT; ++t) {
        int k0 = t * 64;

        // issue order matters for vmcnt: V(2), bias(4), K(2).
        stageV(k0);
        f32x4 bb[4];
#pragma unroll
        for (int kt = 0; kt < 4; ++kt) {
            int col = k0 + kt * 16 + lr;
            int col_c = col < N_ ? col : (N_ - 1);
            bb[kt] = *reinterpret_cast<const f32x4*>(
                bp + (size_t)col_c * BPAD_ + q0 + lg * 4);
        }
        __builtin_amdgcn_sched_barrier(0);   // pin bias before K-stage
        if (t + 1 < NT) stageK(cur ^ 1, k0 + 64);
        __builtin_amdgcn_sched_barrier(0);

        // S = Q K^T from LDS (swizzled reads)
        f32x4 s[4];
        __builtin_amdgcn_s_setprio(1);
#pragma unroll
        for (int kt = 0; kt < 4; ++kt) {
            int r = kt * 16 + lr;
            bf16x8 kf0 = *reinterpret_cast<const bf16x8*>(
                Kl[cur] + r * 128 + ((lg ^ (r & 7)) << 4));
            bf16x8 kf1 = *reinterpret_cast<const bf16x8*>(
                Kl[cur] + r * 128 + (((4 + lg) ^ (r & 7)) << 4));
            f32x4 a = {};
            a = __builtin_amdgcn_mfma_f32_16x16x32_bf16(aQ0, kf0, a, 0, 0, 0);
            a = __builtin_amdgcn_mfma_f32_16x16x32_bf16(aQ1, kf1, a, 0, 0, 0);
            s[kt] = a;
        }
        __builtin_amdgcn_s_setprio(0);

        // scale + bias (mask only on last tile)
#pragma unroll
        for (int kt = 0; kt < 4; ++kt)
#pragma unroll
            for (int j = 0; j < 4; ++j)
                s[kt][j] = s[kt][j] * SCALE_ + bb[kt][j];
        if (t == NT - 1) {
#pragma unroll
            for (int kt = 0; kt < 4; ++kt) {
                bool colv = (k0 + kt * 16 + lr) < N_;
#pragma unroll
                for (int j = 0; j < 4; ++j)
                    s[kt][j] = colv ? s[kt][j] : -1e30f;
            }
        }

        // online softmax with defer-max (THR=8, log2 domain)
        float pmax[4];
#pragma unroll
        for (int j = 0; j < 4; ++j) {
            float mx = fmaxf(fmaxf(s[0][j], s[1][j]), fmaxf(s[2][j], s[3][j]));
#pragma unroll
            for (int d = 1; d < 16; d <<= 1) mx = fmaxf(mx, __shfl_xor(mx, d));
            pmax[j] = mx;
        }
        bool need = !(pmax[0] <= mr[0] + 8.f && pmax[1] <= mr[1] + 8.f &&
                      pmax[2] <= mr[2] + 8.f && pmax[3] <= mr[3] + 8.f);
        if (__any(need)) {
#pragma unroll
            for (int j = 0; j < 4; ++j) {
                float mn = fmaxf(mr[j], pmax[j]);
                float sc = __builtin_amdgcn_exp2f(mr[j] - mn);
                mr[j] = mn;
                sr[j] *= sc;
                o[0][j] *= sc; o[1][j] *= sc; o[2][j] *= sc; o[3][j] *= sc;
            }
        }
#pragma unroll
        for (int j = 0; j < 4; ++j) {
            float rs = 0.f;
#pragma unroll
            for (int kt = 0; kt < 4; ++kt) {
                float p = __builtin_amdgcn_exp2f(s[kt][j] - mr[j]);
                s[kt][j] = p;
                rs += p;
            }
#pragma unroll
            for (int d = 1; d < 16; d <<= 1) rs += __shfl_xor(rs, d);
            sr[j] += rs;
        }

        // P -> per-wave LDS (swizzled)
#pragma unroll
        for (int kt = 0; kt < 4; ++kt) {
#pragma unroll
            for (int j = 0; j < 4; ++j) {
                int row = lg * 4 + j;
                int byte = row * 128 + (kt * 16 + lr) * 2;
                byte ^= (row & 7) << 4;
                *reinterpret_cast<bf16_t*>(Pw + byte) = (bf16_t)s[kt][j];
            }
        }

        // V(t) landed? (V loads are the oldest in flight)
        if (t + 1 < NT) asm volatile("s_waitcnt vmcnt(2)" ::: "memory");
        else            asm volatile("s_waitcnt vmcnt(0)" ::: "memory");
        __builtin_amdgcn_s_barrier();
        __builtin_amdgcn_sched_barrier(0);

        // O += P V from LDS
        __builtin_amdgcn_s_setprio(1);
#pragma unroll
        for (int kc = 0; kc < 2; ++kc) {
            int pbyte = lr * 128 + kc * 64 + lg * 16;
            pbyte ^= (lr & 7) << 4;
            bf16x8 aP = *reinterpret_cast<const bf16x8*>(Pw + pbyte);
#pragma unroll
            for (int ft = 0; ft < 4; ++ft) {
                int d = ft * 16 + lr;
                bf16x8 bV = *reinterpret_cast<const bf16x8*>(
                    Vl + d * 128 + (((kc * 4 + lg) ^ (d & 7)) << 4));
                o[ft] = __builtin_amdgcn_mfma_f32_16x16x32_bf16(aP, bV, o[ft], 0, 0, 0);
            }
        }
        __builtin_amdgcn_s_setprio(0);
        __builtin_amdgcn_sched_barrier(0);

        // K(t+1) landed; all waves done with V before next restage
        asm volatile("s_waitcnt vmcnt(0)" ::: "memory");
        __builtin_amdgcn_s_barrier();
        __builtin_amdgcn_sched_barrier(0);
        cur ^= 1;
    }

#pragma unroll
    for (int j = 0; j < 4; ++j) {
        int row = q0 + lg * 4 + j;
        if (row < N_) {
            float inv = 1.f / sr[j];
#pragma unroll
            for (int ft = 0; ft < 4; ++ft) {
                out[((size_t)(b * N_ + row)) * D_ + h * HD_ + ft * 16 + lr] = o[ft][j] * inv;
            }
        }
    }
}

// ---------------------------------------------------------------- launch
extern "C" void kernel_launch(void* const* d_in, const int* in_sizes, int n_in,
                              void* d_out, int out_size, void* d_ws, size_t ws_size,
                              hipStream_t stream)
{
    const float* hs    = (const float*)d_in[0];
    const float* q_w   = (const float*)d_in[1];
    const float* q_b   = (const float*)d_in[2];
    const float* k_w   = (const float*)d_in[3];
    const float* v_w   = (const float*)d_in[4];
    const float* v_b   = (const float*)d_in[5];
    const float* table = (const float*)d_in[6];
    const int*   rpi   = (const int*)d_in[7];
    float* out = (float*)d_out;

    char* ws = (char*)d_ws;
    size_t off = 0;
    auto alloc = [&](size_t bytes) {
        char* p = ws + off;
        off = (off + bytes + 255) & ~(size_t)255;
        return p;
    };
    bf16_t* hb  = (bf16_t*)alloc((size_t)M_ * D_ * 2);
    bf16_t* Wc  = (bf16_t*)alloc((size_t)NW_ * D_ * 2);
    bf16_t* Qb  = (bf16_t*)alloc((size_t)B_ * H_ * N_ * HD_ * 2);
    bf16_t* Kb  = (bf16_t*)alloc((size_t)B_ * H_ * N_ * HD_ * 2);
    bf16_t* VTb = (bf16_t*)alloc((size_t)B_ * H_ * HD_ * VN_ * 2);
    float*  bia = (float*)alloc((size_t)H_ * N_ * BPAD_ * 4);

    int n4h = M_ * D_ / 4;
    cvt_f32_bf16<<<(n4h + 255) / 256, 256, 0, stream>>>(hs, hb, n4h);
    int n4w = D_ * D_ / 4;
    cvt3_f32_bf16<<<dim3((n4w + 255) / 256, 3), 256, 0, stream>>>(
        q_w, k_w, v_w, Wc, n4w);
    build_bias_t<<<dim3(N_, H_), 256, 0, stream>>>(table, rpi, bia);

    qkv_gemm<<<2610, 256, 0, stream>>>(hb, Wc, q_b, v_b, Qb, Kb, VTb);

    attn<<<3840, 256, 0, stream>>>(Qb, Kb, VTb, bia, out);
}

// Round 7
// 231.401 us; speedup vs baseline: 3.6052x; 1.1545x over previous
//
#include <hip/hip_runtime.h>
#include <hip/hip_bf16.h>

#define B_  32
#define N_  577
#define D_  768
#define H_  12
#define HD_ 64
#define M_  (B_ * N_)        // 18464 rows
#define NW_ (3 * D_)         // 2304 fused output cols (q|k|v)
#define VN_ 640              // padded V row stride
#define BPAD_ 580            // bias row-dim padding (mult of 4)
#define SCALE_ 0.18033688f   // 0.125 * log2(e)

typedef __bf16 bf16_t;
typedef __bf16 bf16x8 __attribute__((ext_vector_type(8)));
typedef __bf16 bf16x4 __attribute__((ext_vector_type(4)));
typedef float  f32x4  __attribute__((ext_vector_type(4)));

static __device__ __forceinline__ bf16x8 ldg8(const bf16_t* p) {
    return *reinterpret_cast<const bf16x8*>(p);
}

#define GLOAD_LDS16(g, l)                                                     \
    __builtin_amdgcn_global_load_lds(                                         \
        (const __attribute__((address_space(1))) void*)(g),                   \
        (__attribute__((address_space(3))) void*)(l), 16, 0, 0)

// ---------------------------------------------------------------- fp32->bf16
__global__ void cvt_f32_bf16(const float* __restrict__ src,
                             bf16_t* __restrict__ dst, int n4) {
    int i = blockIdx.x * blockDim.x + threadIdx.x;
    if (i < n4) {
        float4 f = reinterpret_cast<const float4*>(src)[i];
        bf16x4 o;
        o.x = (bf16_t)f.x; o.y = (bf16_t)f.y; o.z = (bf16_t)f.z; o.w = (bf16_t)f.w;
        *reinterpret_cast<bf16x4*>(dst + (size_t)i * 4) = o;
    }
}

// three weight matrices in one launch (blockIdx.y selects)
__global__ void cvt3_f32_bf16(const float* __restrict__ s0,
                              const float* __restrict__ s1,
                              const float* __restrict__ s2,
                              bf16_t* __restrict__ dst, int n4) {
    int i = blockIdx.x * blockDim.x + threadIdx.x;
    if (i < n4) {
        const float* src = blockIdx.y == 0 ? s0 : (blockIdx.y == 1 ? s1 : s2);
        float4 f = reinterpret_cast<const float4*>(src)[i];
        bf16x4 o;
        o.x = (bf16_t)f.x; o.y = (bf16_t)f.y; o.z = (bf16_t)f.z; o.w = (bf16_t)f.w;
        *reinterpret_cast<bf16x4*>(dst + (size_t)blockIdx.y * n4 * 4 + (size_t)i * 4) = o;
    }
}

// ---------------------------------------------------------------- bias build
// biasT[h][col][row] = table[idx[row][col]*H + h] * log2(e)   (row padded)
__global__ void build_bias_t(const float* __restrict__ table,
                             const int* __restrict__ idx,
                             float* __restrict__ biasT) {
    int col = blockIdx.x;   // key col
    int h   = blockIdx.y;   // head
    for (int row = threadIdx.x; row < BPAD_; row += blockDim.x) {
        int rr = row < N_ ? row : (N_ - 1);
        int id = idx[rr * N_ + col];
        biasT[((size_t)h * N_ + col) * BPAD_ + row] =
            table[id * H_ + h] * 1.44269504f;
    }
}

// ---------------------------------------------------------------- QKV GEMM
__global__ __launch_bounds__(256) void qkv_gemm(
    const bf16_t* __restrict__ hb, const bf16_t* __restrict__ W,
    const float* __restrict__ qb, const float* __restrict__ vb,
    bf16_t* __restrict__ Q, bf16_t* __restrict__ K, bf16_t* __restrict__ VT)
{
    __shared__ __align__(16) char lds[65536];  // A:[2][16K] @0, B:[2][16K] @32K

    int tid = threadIdx.x;
    int w  = tid >> 6, l = tid & 63;
    int lr = l & 15, lg = l >> 4;
    int wm = w & 1,  wn = w >> 1;

    int wg = blockIdx.x;
    int xcd = wg & 7, pos = wg >> 3;
    const int Q8 = 2610 / 8, R8 = 2610 % 8;   // 326, 2
    int base = xcd < R8 ? xcd * (Q8 + 1) : R8 * (Q8 + 1) + (xcd - R8) * Q8;
    int wgid = base + pos;
    int bx = wgid / 18, y = wgid - bx * 18;
    int brow = bx * 128;
    int mat = y / 6, ysub = y - mat * 6;
    int cbase = ysub * 128;

    int srow = tid >> 3;
    int sslot = (tid & 7) ^ (srow & 7);
    const bf16_t* pa[4];
    const bf16_t* pb[4];
#pragma unroll
    for (int r = 0; r < 4; ++r) {
        int ra = brow + r * 32 + srow; ra = ra < M_ ? ra : (M_ - 1);
        pa[r] = hb + (size_t)ra * D_ + sslot * 8;
        pb[r] = W + (size_t)(y * 128 + r * 32 + srow) * D_ + sslot * 8;
    }

    auto stage = [&](int buf, int k) {
#pragma unroll
        for (int r = 0; r < 4; ++r) {
            GLOAD_LDS16(pa[r] + k, lds + buf * 16384 + r * 4096 + tid * 16);
            GLOAD_LDS16(pb[r] + k, lds + 32768 + buf * 16384 + r * 4096 + tid * 16);
        }
    };

    f32x4 acc[4][4] = {};
    stage(0, 0);
    int cur = 0;
    for (int t = 0; t < 12; ++t) {
        if (t < 11) {
            stage(cur ^ 1, (t + 1) * 64);
            asm volatile("s_waitcnt vmcnt(8)" ::: "memory");
        } else {
            asm volatile("s_waitcnt vmcnt(0)" ::: "memory");
        }
        __builtin_amdgcn_s_barrier();
        __builtin_amdgcn_sched_barrier(0);

        const char* pA = lds + cur * 16384;
        const char* pB = lds + 32768 + cur * 16384;
#pragma unroll
        for (int kk = 0; kk < 2; ++kk) {
            bf16x8 af[4];
#pragma unroll
            for (int m = 0; m < 4; ++m) {
                int row = wm * 64 + m * 16 + lr;
                af[m] = *reinterpret_cast<const bf16x8*>(
                    pA + row * 128 + (((kk * 4 + lg) ^ (lr & 7)) << 4));
            }
#pragma unroll
            for (int n = 0; n < 4; ++n) {
                int row = wn * 64 + n * 16 + lr;
                bf16x8 bfr = *reinterpret_cast<const bf16x8*>(
                    pB + row * 128 + (((kk * 4 + lg) ^ (lr & 7)) << 4));
#pragma unroll
                for (int m = 0; m < 4; ++m)
                    acc[m][n] = __builtin_amdgcn_mfma_f32_16x16x32_bf16(
                        af[m], bfr, acc[m][n], 0, 0, 0);
            }
        }
        __builtin_amdgcn_sched_barrier(0);
        __builtin_amdgcn_s_barrier();
        cur ^= 1;
    }

    bf16_t* ep = (bf16_t*)lds;
    if (mat < 2) {
#pragma unroll
        for (int m = 0; m < 4; ++m)
#pragma unroll
            for (int n = 0; n < 4; ++n) {
                int col = wn * 64 + n * 16 + lr;
                float badd = (mat == 0) ? qb[cbase + col] : 0.f;
#pragma unroll
                for (int j = 0; j < 4; ++j) {
                    int row = wm * 64 + m * 16 + lg * 4 + j;
                    ep[row * 132 + col] = (bf16_t)(acc[m][n][j] + badd);
                }
            }
        __syncthreads();
        bf16_t* dst0 = (mat == 0) ? Q : K;
#pragma unroll
        for (int k = 0; k < 8; ++k) {
            int c = k * 256 + tid;
            int row = c >> 4, cc = c & 15;
            int grow = brow + row;
            if (grow < M_) {
                int bb = grow / N_, nn = grow - bb * N_;
                int col0 = cc * 8;
                int hh = ysub * 2 + (col0 >> 6);
                int hd0 = col0 & 63;
                bf16x8 vc = *reinterpret_cast<const bf16x8*>(ep + row * 132 + col0);
                *reinterpret_cast<bf16x8*>(
                    dst0 + ((size_t)(bb * H_ + hh) * N_ + nn) * HD_ + hd0) = vc;
            }
        }
    } else {
#pragma unroll
        for (int m = 0; m < 4; ++m)
#pragma unroll
            for (int n = 0; n < 4; ++n) {
                int col = wn * 64 + n * 16 + lr;
                float badd = vb[cbase + col];
#pragma unroll
                for (int j = 0; j < 4; ++j) {
                    int row = wm * 64 + m * 16 + lg * 4 + j;
                    ep[col * 132 + row] = (bf16_t)(acc[m][n][j] + badd);
                }
            }
        __syncthreads();
#pragma unroll
        for (int k = 0; k < 8; ++k) {
            int c = k * 256 + tid;
            int col = c >> 4, rc = c & 15;
            int grow0 = brow + rc * 8;
            int hh = ysub * 2 + (col >> 6), hd = col & 63;
            int bb = grow0 / N_, nn0 = grow0 - bb * N_;
            if (nn0 + 8 <= N_ && grow0 + 8 <= M_) {
                *reinterpret_cast<bf16x8*>(
                    VT + ((size_t)(bb * H_ + hh) * HD_ + hd) * VN_ + nn0) =
                    *reinterpret_cast<const bf16x8*>(ep + col * 132 + rc * 8);
            } else {
                for (int jj = 0; jj < 8; ++jj) {
                    int grow = grow0 + jj;
                    if (grow >= M_) break;
                    int b2 = grow / N_, n2 = grow - b2 * N_;
                    VT[((size_t)(b2 * H_ + hh) * HD_ + hd) * VN_ + n2] =
                        ep[col * 132 + rc * 8 + jj];
                }
            }
        }
    }
}

// ---------------------------------------------------------------- attention
// 4 waves x 16 q-rows; K dbuf, V single-buf; steady-state softmax has NO
// cross-lane reduces: lazy max (local max + __any ballot, full reduce only
// on trigger) + row-sum via ones-MFMA on the matrix pipe.
__global__ __launch_bounds__(256) void attn(
    const bf16_t* __restrict__ Q, const bf16_t* __restrict__ K,
    const bf16_t* __restrict__ VT, const float* __restrict__ biasT,
    float* __restrict__ out)
{
    __shared__ __align__(16) char Kl[2][8192];   // [64 key][64 hd] bf16, swz
    __shared__ __align__(16) char Vl[8192];      // [64 d][64 key] bf16, swz
    __shared__ __align__(16) char Pl[4][2048];   // per-wave P, swz

    int tid = threadIdx.x;
    int w = tid >> 6, l = tid & 63, lr = l & 15, lg = l >> 4;

    int wg = blockIdx.x;
    int wgid = (wg & 7) * 480 + (wg >> 3);
    int h = wgid / 320;
    int rem = wgid - h * 320;
    int b = rem / 10;
    int qt = rem - b * 10;

    const bf16_t* Qp = Q  + (size_t)(b * H_ + h) * N_ * HD_;
    const bf16_t* Kp = K  + (size_t)(b * H_ + h) * N_ * HD_;
    const bf16_t* Vp = VT + (size_t)(b * H_ + h) * HD_ * VN_;
    const float*  bp = biasT + (size_t)h * N_ * BPAD_;   // [col][row]

    int q0 = qt * 64 + w * 16;
    int qrow = q0 + lr;
    int qrow_c = qrow < N_ ? qrow : (N_ - 1);
    bf16x8 aQ0 = ldg8(Qp + (size_t)qrow_c * HD_ + lg * 8);
    bf16x8 aQ1 = ldg8(Qp + (size_t)qrow_c * HD_ + 32 + lg * 8);

    bf16x8 vone;
#pragma unroll
    for (int i = 0; i < 8; ++i) vone[i] = (bf16_t)1.0f;

    int rloc = l >> 3;              // 0..7
    int cswz = (l & 7) ^ rloc;      // swizzled 8-elem column

    f32x4 o[4] = {};
    f32x4 osum = {};                // row sums via ones-MFMA
    float mr[4] = {-INFINITY, -INFINITY, -INFINITY, -INFINITY};
    char* Pw = Pl[w];

    auto stageK = [&](int buf, int k0) {
#pragma unroll
        for (int round = 0; round < 2; ++round) {
            int r = round * 32 + w * 8 + rloc;
            int kr = k0 + r; kr = kr < N_ ? kr : (N_ - 1);
            GLOAD_LDS16(Kp + (size_t)kr * HD_ + cswz * 8,
                        Kl[buf] + round * 4096 + w * 1024);
        }
    };
    auto stageV = [&](int k0) {
#pragma unroll
        for (int round = 0; round < 2; ++round) {
            int r = round * 32 + w * 8 + rloc;
            GLOAD_LDS16(Vp + (size_t)r * VN_ + k0 + cswz * 8,
                        Vl + round * 4096 + w * 1024);
        }
    };

    stageK(0, 0);
    __syncthreads();

    int cur = 0;
    const int NT = (N_ + 63) / 64;   // 10
    for (int t = 0; t < NT; ++t) {
        int k0 = t * 64;

        // issue order matters for vmcnt: V(2), bias(4), K(2).
        stageV(k0);
        f32x4 bb[4];
#pragma unroll
        for (int kt = 0; kt < 4; ++kt) {
            int col = k0 + kt * 16 + lr;
            int col_c = col < N_ ? col : (N_ - 1);
            bb[kt] = *reinterpret_cast<const f32x4*>(
                bp + (size_t)col_c * BPAD_ + q0 + lg * 4);
        }
        __builtin_amdgcn_sched_barrier(0);   // pin bias before K-stage
        if (t + 1 < NT) stageK(cur ^ 1, k0 + 64);
        __builtin_amdgcn_sched_barrier(0);

        // S = Q K^T from LDS (swizzled reads)
        f32x4 s[4];
        __builtin_amdgcn_s_setprio(1);
#pragma unroll
        for (int kt = 0; kt < 4; ++kt) {
            int r = kt * 16 + lr;
            bf16x8 kf0 = *reinterpret_cast<const bf16x8*>(
                Kl[cur] + r * 128 + ((lg ^ (r & 7)) << 4));
            bf16x8 kf1 = *reinterpret_cast<const bf16x8*>(
                Kl[cur] + r * 128 + (((4 + lg) ^ (r & 7)) << 4));
            f32x4 a = {};
            a = __builtin_amdgcn_mfma_f32_16x16x32_bf16(aQ0, kf0, a, 0, 0, 0);
            a = __builtin_amdgcn_mfma_f32_16x16x32_bf16(aQ1, kf1, a, 0, 0, 0);
            s[kt] = a;
        }
        __builtin_amdgcn_s_setprio(0);

        // scale + bias (mask only on last tile)
#pragma unroll
        for (int kt = 0; kt < 4; ++kt)
#pragma unroll
            for (int j = 0; j < 4; ++j)
                s[kt][j] = s[kt][j] * SCALE_ + bb[kt][j];
        if (t == NT - 1) {
#pragma unroll
            for (int kt = 0; kt < 4; ++kt) {
                bool colv = (k0 + kt * 16 + lr) < N_;
#pragma unroll
                for (int j = 0; j < 4; ++j)
                    s[kt][j] = colv ? s[kt][j] : -1e30f;
            }
        }

        // lazy-max online softmax: steady state = local max + ballot only
        float lmax[4];
#pragma unroll
        for (int j = 0; j < 4; ++j)
            lmax[j] = fmaxf(fmaxf(s[0][j], s[1][j]), fmaxf(s[2][j], s[3][j]));
        bool need = (lmax[0] > mr[0] + 8.f) || (lmax[1] > mr[1] + 8.f) ||
                    (lmax[2] > mr[2] + 8.f) || (lmax[3] > mr[3] + 8.f);
        if (__any(need)) {
            // full row-max reduce + rescale (rare: tile 0 + drift >8)
#pragma unroll
            for (int j = 0; j < 4; ++j) {
                float mx = lmax[j];
#pragma unroll
                for (int d = 1; d < 16; d <<= 1) mx = fmaxf(mx, __shfl_xor(mx, d));
                float mn = fmaxf(mr[j], mx);
                float sc = __builtin_amdgcn_exp2f(mr[j] - mn);
                mr[j] = mn;
                o[0][j] *= sc; o[1][j] *= sc; o[2][j] *= sc; o[3][j] *= sc;
                osum[j] *= sc;
            }
        }
#pragma unroll
        for (int kt = 0; kt < 4; ++kt)
#pragma unroll
            for (int j = 0; j < 4; ++j)
                s[kt][j] = __builtin_amdgcn_exp2f(s[kt][j] - mr[j]);

        // P -> per-wave LDS (swizzled)
#pragma unroll
        for (int kt = 0; kt < 4; ++kt) {
#pragma unroll
            for (int j = 0; j < 4; ++j) {
                int row = lg * 4 + j;
                int byte = row * 128 + (kt * 16 + lr) * 2;
                byte ^= (row & 7) << 4;
                *reinterpret_cast<bf16_t*>(Pw + byte) = (bf16_t)s[kt][j];
            }
        }

        // V(t) landed? (V loads are the oldest in flight)
        if (t + 1 < NT) asm volatile("s_waitcnt vmcnt(2)" ::: "memory");
        else            asm volatile("s_waitcnt vmcnt(0)" ::: "memory");
        __builtin_amdgcn_s_barrier();
        __builtin_amdgcn_sched_barrier(0);

        // O += P V from LDS; row-sum += P * ones (matrix pipe)
        __builtin_amdgcn_s_setprio(1);
#pragma unroll
        for (int kc = 0; kc < 2; ++kc) {
            int pbyte = lr * 128 + kc * 64 + lg * 16;
            pbyte ^= (lr & 7) << 4;
            bf16x8 aP = *reinterpret_cast<const bf16x8*>(Pw + pbyte);
            osum = __builtin_amdgcn_mfma_f32_16x16x32_bf16(aP, vone, osum, 0, 0, 0);
#pragma unroll
            for (int ft = 0; ft < 4; ++ft) {
                int d = ft * 16 + lr;
                bf16x8 bV = *reinterpret_cast<const bf16x8*>(
                    Vl + d * 128 + (((kc * 4 + lg) ^ (d & 7)) << 4));
                o[ft] = __builtin_amdgcn_mfma_f32_16x16x32_bf16(aP, bV, o[ft], 0, 0, 0);
            }
        }
        __builtin_amdgcn_s_setprio(0);
        __builtin_amdgcn_sched_barrier(0);

        // K(t+1) landed; all waves done with V before next restage
        asm volatile("s_waitcnt vmcnt(0)" ::: "memory");
        __builtin_amdgcn_s_barrier();
        __builtin_amdgcn_sched_barrier(0);
        cur ^= 1;
    }

#pragma unroll
    for (int j = 0; j < 4; ++j) {
        int row = q0 + lg * 4 + j;
        if (row < N_) {
            float inv = 1.f / osum[j];
#pragma unroll
            for (int ft = 0; ft < 4; ++ft) {
                out[((size_t)(b * N_ + row)) * D_ + h * HD_ + ft * 16 + lr] = o[ft][j] * inv;
            }
        }
    }
}

// ---------------------------------------------------------------- launch
extern "C" void kernel_launch(void* const* d_in, const int* in_sizes, int n_in,
                              void* d_out, int out_size, void* d_ws, size_t ws_size,
                              hipStream_t stream)
{
    const float* hs    = (const float*)d_in[0];
    const float* q_w   = (const float*)d_in[1];
    const float* q_b   = (const float*)d_in[2];
    const float* k_w   = (const float*)d_in[3];
    const float* v_w   = (const float*)d_in[4];
    const float* v_b   = (const float*)d_in[5];
    const float* table = (const float*)d_in[6];
    const int*   rpi   = (const int*)d_in[7];
    float* out = (float*)d_out;

    char* ws = (char*)d_ws;
    size_t off = 0;
    auto alloc = [&](size_t bytes) {
        char* p = ws + off;
        off = (off + bytes + 255) & ~(size_t)255;
        return p;
    };
    bf16_t* hb  = (bf16_t*)alloc((size_t)M_ * D_ * 2);
    bf16_t* Wc  = (bf16_t*)alloc((size_t)NW_ * D_ * 2);
    bf16_t* Qb  = (bf16_t*)alloc((size_t)B_ * H_ * N_ * HD_ * 2);
    bf16_t* Kb  = (bf16_t*)alloc((size_t)B_ * H_ * N_ * HD_ * 2);
    bf16_t* VTb = (bf16_t*)alloc((size_t)B_ * H_ * HD_ * VN_ * 2);
    float*  bia = (float*)alloc((size_t)H_ * N_ * BPAD_ * 4);

    int n4h = M_ * D_ / 4;
    cvt_f32_bf16<<<(n4h + 255) / 256, 256, 0, stream>>>(hs, hb, n4h);
    int n4w = D_ * D_ / 4;
    cvt3_f32_bf16<<<dim3((n4w + 255) / 256, 3), 256, 0, stream>>>(
        q_w, k_w, v_w, Wc, n4w);
    build_bias_t<<<dim3(N_, H_), 256, 0, stream>>>(table, rpi, bia);

    qkv_gemm<<<2610, 256, 0, stream>>>(hb, Wc, q_b, v_b, Qb, Kb, VTb);

    attn<<<3840, 256, 0, stream>>>(Qb, Kb, VTb, bia, out);
}